// Round 9
// baseline (959.871 us; speedup 1.0000x reference)
//
#include <hip/hip_runtime.h>

#define BT 6272      // B*T = 32*196
#define TT 196
#define DM 512
#define FFD 2048
#define NE 8
#define ABUF 3211264 // activation buffer elems (6272*512)
#define SLOTS 12544  // BT*2 expert slots

typedef float f32x4 __attribute__((ext_vector_type(4)));
typedef __bf16 bf16x8 __attribute__((ext_vector_type(8)));

__device__ __forceinline__ ushort f2bf(float f){
  union { float f; unsigned u; } v; v.f = f;
  unsigned u = v.u;
  u += 0x7fffu + ((u >> 16) & 1u);   // RNE
  return (ushort)(u >> 16);
}
__device__ __forceinline__ float bf2f(ushort u){
  union { unsigned u; float f; } c; c.u = ((unsigned)u) << 16; return c.f;
}
// split fp32 into bf16 hi (truncated) + bf16 lo (RNE of remainder): a ~= hi + lo, err ~2^-17
__device__ __forceinline__ void splitbf(float v, ushort& hi, ushort& lo){
  union { float f; unsigned u; } c; c.f = v;
  hi = (ushort)(c.u >> 16);
  union { unsigned u; float f; } hf; hf.u = c.u & 0xffff0000u;
  lo = f2bf(v - hf.f);
}
// async global->LDS 16B: lds dest is wave-uniform base (lane writes base+lane*16)
__device__ __forceinline__ void glds16(const ushort* g, ushort* l){
  __builtin_amdgcn_global_load_lds(
      (const __attribute__((address_space(1))) unsigned int*)g,
      (__attribute__((address_space(3))) unsigned int*)l, 16, 0, 0);
}
// bijective XCD-chunked block remap (m204): contiguous work per XCD
__device__ __forceinline__ int xcd_swz(int f, int nwg){
  int q = nwg >> 3, r = nwg & 7;
  int xcd = f & 7, i = f >> 3;
  return (xcd < r ? xcd*(q+1) : r*(q+1) + (xcd-r)*q) + i;
}

// ---------------- patchify: x[B,1,224,224] f32 -> split-bf16 patches[BT,256] ----------------
__global__ void patchify_k(const float* __restrict__ x, ushort* __restrict__ oh, ushort* __restrict__ ol){
  int bt = blockIdx.x;
  int t = bt % TT, b = bt / TT;
  int pd = threadIdx.x;
  int g1 = t / 14, g2 = t % 14, p1 = pd >> 4, p2 = pd & 15;
  int src = (b*224 + g1*16 + p1)*224 + g2*16 + p2;
  float v = x[src];
  ushort hu, lu; splitbf(v, hu, lu);
  oh[(size_t)bt*256 + pd] = hu;
  ol[(size_t)bt*256 + pd] = lu;
}

// ---------------- posenc[196,512] f32 ----------------
__global__ void posenc_k(float* __restrict__ pe){
  int t = blockIdx.x, c = threadIdx.x;
  int m2 = c & ~1;
  double ang = (double)t * pow(10000.0, -(double)m2 / 512.0);
  double vv = (c & 1) ? cos(ang) : sin(ang);
  pe[t*DM + c] = (float)vv;
}

// ---------------- weight transpose + split: src[R][C] f32 -> dh/dl[C][R] bf16 hi/lo ----------------
__global__ __launch_bounds__(256)
void wsplit_k(const float* __restrict__ src, ushort* __restrict__ dh, ushort* __restrict__ dl,
              int R, int C){
  __shared__ float t[32][33];
  int c0 = blockIdx.x << 5, r0 = blockIdx.y << 5;
  int tx = threadIdx.x & 31, ty = threadIdx.x >> 5;
  #pragma unroll
  for (int i = 0; i < 32; i += 8)
    t[ty+i][tx] = src[(size_t)(r0+ty+i)*C + c0 + tx];
  __syncthreads();
  #pragma unroll
  for (int i = 0; i < 32; i += 8){
    float v = t[tx][ty+i];
    ushort hu, lu; splitbf(v, hu, lu);
    dh[(size_t)(c0+ty+i)*R + r0 + tx] = hu;
    dl[(size_t)(c0+ty+i)*R + r0 + tx] = lu;
  }
}

// ------- batched 5-way: z=0..2 Wq/Wk/Wv transpose->QkvW; z=3 Wo transpose->WoS; z=4 pW elementwise ----
__global__ __launch_bounds__(256)
void wsplit5e_k(const float* __restrict__ s0, const float* __restrict__ s1,
                const float* __restrict__ s2, const float* __restrict__ s3,
                const float* __restrict__ s4,
                ushort* __restrict__ dQkvH, ushort* __restrict__ dQkvL,
                ushort* __restrict__ dWoH, ushort* __restrict__ dWoL,
                ushort* __restrict__ dPWh, ushort* __restrict__ dPWl)
{
  int z = blockIdx.z;
  int c0 = blockIdx.x << 5, r0 = blockIdx.y << 5;
  int tx = threadIdx.x & 31, ty = threadIdx.x >> 5;
  if (z == 4){   // elementwise split of pW (no transpose)
    #pragma unroll
    for (int i = 0; i < 32; i += 8){
      size_t idx = (size_t)(r0+ty+i)*DM + c0 + tx;
      ushort hu, lu; splitbf(s4[idx], hu, lu);
      dPWh[idx] = hu; dPWl[idx] = lu;
    }
    return;
  }
  const float* src = (z==0)? s0 : (z==1)? s1 : (z==2)? s2 : s3;
  ushort* dh; ushort* dl;
  if (z == 3){ dh = dWoH; dl = dWoL; }
  else { dh = dQkvH + (size_t)z*DM*DM; dl = dQkvL + (size_t)z*DM*DM; }
  __shared__ float t[32][33];
  #pragma unroll
  for (int i = 0; i < 32; i += 8)
    t[ty+i][tx] = src[(size_t)(r0+ty+i)*DM + c0 + tx];
  __syncthreads();
  #pragma unroll
  for (int i = 0; i < 32; i += 8){
    float v = t[tx][ty+i];
    ushort hu, lu; splitbf(v, hu, lu);
    dh[(size_t)(c0+ty+i)*DM + r0 + tx] = hu;
    dl[(size_t)(c0+ty+i)*DM + r0 + tx] = lu;
  }
}

// ---------------- folded QKV bias: bf[n] = sum_d pb[d] * Wqkv[d][n]; wave-per-n ----------
__global__ __launch_bounds__(256)
void bfold_k(const float* __restrict__ pb, const float* __restrict__ Wq,
             const float* __restrict__ Wk, const float* __restrict__ Wv,
             float* __restrict__ bf){
  int tid = threadIdx.x;
  int w = tid >> 6, lane = tid & 63;
  int n = blockIdx.x*4 + w;            // grid 384 -> n in [0,1536)
  const float* W = (n < 512) ? Wq : (n < 1024) ? Wk : Wv;
  int c = n & 511;
  float s = 0.f;
  #pragma unroll
  for (int u = 0; u < 8; ++u){
    int d = (u<<6) + lane;
    s += pb[d] * W[(size_t)d*DM + c];
  }
  #pragma unroll
  for (int off = 32; off; off >>= 1) s += __shfl_xor(s, off, 64);
  if (lane == 0) bf[n] = s;
}

// ---------------- dense split-bf16 MFMA GEMM, 128x128 tile, counted-vmcnt 2-deep pipeline --
// LDS bounce epilogue for split-bf16 outputs (full-line vectorized stores).
__global__ __launch_bounds__(256)
void gemm_s(const ushort* __restrict__ Ah, const ushort* __restrict__ Al,
            const ushort* __restrict__ Bh, const ushort* __restrict__ Bl,
            const float* __restrict__ bias, const float* __restrict__ pe,
            float* __restrict__ Cf, ushort* __restrict__ Ch, ushort* __restrict__ Cl,
            int N, int kld)
{
  __shared__ __align__(16) ushort smem[4][2*128*32];   // Ahs/Als/Bhs/Bls, 16KB each
  ushort* Ahs = smem[0];
  ushort* Als = smem[1];
  ushort* Bhs = smem[2];
  ushort* Bls = smem[3];
  int gx = gridDim.x, gy = gridDim.y;
  int fblk = blockIdx.x + gx*blockIdx.y;
  int wgt = xcd_swz(fblk, gx*gy);
  int bx = wgt % gx, by = wgt / gx;
  int row0 = by << 7, col0 = bx << 7;
  int tid = threadIdx.x;
  int lane = tid & 63, w = tid >> 6;
  int wr = w >> 1, wc = w & 1;
  int fr = lane & 15, fu = lane >> 4;
  int srow = 16*w + (lane >> 2);
  int cs = ((lane & 3) ^ ((srow >> 1) & 3)) << 3;   // pre-swizzled source chunk (shorts)
  const ushort* gAh0 = Ah + (size_t)(row0 + srow) * kld + cs;
  const ushort* gAh1 = Ah + (size_t)(row0 + 64 + srow) * kld + cs;
  const ushort* gAl0 = Al + (size_t)(row0 + srow) * kld + cs;
  const ushort* gAl1 = Al + (size_t)(row0 + 64 + srow) * kld + cs;
  const ushort* gBh0 = Bh + (size_t)(col0 + srow) * kld + cs;
  const ushort* gBh1 = Bh + (size_t)(col0 + 64 + srow) * kld + cs;
  const ushort* gBl0 = Bl + (size_t)(col0 + srow) * kld + cs;
  const ushort* gBl1 = Bl + (size_t)(col0 + 64 + srow) * kld + cs;
  int lo0 = (16*w)*32, lo1 = (64+16*w)*32;
  #define GSTAGE(koff, nb) { \
    glds16(gAh0 + (koff), &Ahs[(nb)+lo0]); glds16(gAh1 + (koff), &Ahs[(nb)+lo1]); \
    glds16(gAl0 + (koff), &Als[(nb)+lo0]); glds16(gAl1 + (koff), &Als[(nb)+lo1]); \
    glds16(gBh0 + (koff), &Bhs[(nb)+lo0]); glds16(gBh1 + (koff), &Bhs[(nb)+lo1]); \
    glds16(gBl0 + (koff), &Bls[(nb)+lo0]); glds16(gBl1 + (koff), &Bls[(nb)+lo1]); }
  f32x4 acc[4][4] = {};
  int nt = kld >> 5;
  GSTAGE(0, 0)
  GSTAGE(32, 128*32)
  for (int t = 0; t < nt; ++t){
    if (t + 1 < nt) asm volatile("s_waitcnt vmcnt(8)" ::: "memory");
    else            asm volatile("s_waitcnt vmcnt(0)" ::: "memory");
    __builtin_amdgcn_s_barrier();
    asm volatile("" ::: "memory");
    int cb = (t & 1) * (128*32);
    bf16x8 ah[4], al[4];
    #pragma unroll
    for (int i = 0; i < 4; ++i){
      int Ra = (wr<<6) + (i<<4) + fr;
      int oa = cb + Ra*32 + ((fu ^ ((Ra>>1)&3))<<3);
      ah[i] = *(const bf16x8*)&Ahs[oa];
      al[i] = *(const bf16x8*)&Als[oa];
    }
    #pragma unroll
    for (int j = 0; j < 4; ++j){
      int Rb = (wc<<6) + (j<<4) + fr;
      int ob = cb + Rb*32 + ((fu ^ ((Rb>>1)&3))<<3);
      bf16x8 bh = *(const bf16x8*)&Bhs[ob];
      bf16x8 bl = *(const bf16x8*)&Bls[ob];
      #pragma unroll
      for (int i = 0; i < 4; ++i){
        acc[i][j] = __builtin_amdgcn_mfma_f32_16x16x32_bf16(ah[i], bh, acc[i][j], 0, 0, 0);
        acc[i][j] = __builtin_amdgcn_mfma_f32_16x16x32_bf16(al[i], bh, acc[i][j], 0, 0, 0);
        acc[i][j] = __builtin_amdgcn_mfma_f32_16x16x32_bf16(ah[i], bl, acc[i][j], 0, 0, 0);
      }
    }
    asm volatile("" ::: "memory");
    __builtin_amdgcn_s_barrier();
    if (t + 2 < nt) GSTAGE((t+2) << 5, (t & 1) * (128*32))
  }
  #undef GSTAGE
  int fq = lane >> 4;
  if (Cf){
    #pragma unroll
    for (int j = 0; j < 4; ++j){
      int col = col0 + (wc<<6) + (j<<4) + fr;
      float bv = bias ? bias[col] : 0.f;
      #pragma unroll
      for (int i = 0; i < 4; ++i){
        #pragma unroll
        for (int q = 0; q < 4; ++q){
          int rr = row0 + (wr<<6) + (i<<4) + (fq<<2) + q;
          float v = acc[i][j][q] + bv;
          if (pe) v += pe[(size_t)(rr % TT)*DM + col];
          Cf[(size_t)rr*N + col] = v;
        }
      }
    }
  }
  if (Ch){
    ushort* Lh = smem[0];   // spans smem[0..1]: [128][128] ushorts
    ushort* Ll = smem[2];   // spans smem[2..3]
    __syncthreads();        // all LDS reads from K-loop complete
    #pragma unroll
    for (int j = 0; j < 4; ++j){
      int lcol = (wc<<6) + (j<<4) + fr;
      int col = col0 + lcol;
      float bv = bias ? bias[col] : 0.f;
      #pragma unroll
      for (int i = 0; i < 4; ++i){
        #pragma unroll
        for (int q = 0; q < 4; ++q){
          int lrow = (wr<<6) + (i<<4) + (fq<<2) + q;
          float v = acc[i][j][q] + bv;
          if (pe) v += pe[(size_t)((row0 + lrow) % TT)*DM + col];
          ushort hu, lu; splitbf(v, hu, lu);
          int g = (lrow >> 2) & 7;
          int idx = lrow*128 + ((((lcol>>3) ^ g))<<3) + (lcol & 7);
          Lh[idx] = hu; Ll[idx] = lu;
        }
      }
    }
    __syncthreads();
    #pragma unroll
    for (int pass = 0; pass < 8; ++pass){
      int lrow = pass*16 + (tid >> 4);
      int s = tid & 15;
      int g = (lrow >> 2) & 7;
      int idx = lrow*128 + ((s ^ g)<<3);
      uint4 vh = *(const uint4*)&Lh[idx];
      uint4 vl = *(const uint4*)&Ll[idx];
      size_t off = (size_t)(row0 + lrow)*N + col0 + s*8;
      *(uint4*)&Ch[off] = vh;
      *(uint4*)&Cl[off] = vl;
    }
  }
}

// ---------------- old 64x64 GEMM (kept for the tiny cls matmul, M=32) ----------------
__global__ __launch_bounds__(256)
void gemm_f32(const float* __restrict__ A, const float* __restrict__ Bw,
              float* __restrict__ C, const float* __restrict__ bias,
              float* __restrict__ obf, int M, int N, int K)
{
  __shared__ float As[16][68];
  __shared__ float Bs[16][68];
  int tid = threadIdx.x;
  int row0 = blockIdx.y << 6, col0 = blockIdx.x << 6;
  int ar = tid >> 2, ak = (tid & 3) << 2;
  int bk = tid >> 4, bn = (tid & 15) << 2;
  int n0 = (tid & 15) << 2, m0 = (tid >> 4) << 2;
  float acc[4][4] = {};
  bool arow_ok = (row0 + ar) < M;
  const float* Aldg = A + (size_t)(row0 + ar) * K + ak;
  const float* Bldg = Bw + (size_t)bk * N + col0 + bn;
  for (int k0 = 0; k0 < K; k0 += 16){
    float4 av = make_float4(0.f,0.f,0.f,0.f);
    if (arow_ok) av = *(const float4*)(Aldg + k0);
    float4 bv = *(const float4*)(Bldg + (size_t)k0 * N);
    __syncthreads();
    As[ak+0][ar]=av.x; As[ak+1][ar]=av.y; As[ak+2][ar]=av.z; As[ak+3][ar]=av.w;
    *(float4*)&Bs[bk][bn] = bv;
    __syncthreads();
    #pragma unroll
    for (int kk = 0; kk < 16; ++kk){
      float4 a = *(const float4*)&As[kk][m0];
      float4 b = *(const float4*)&Bs[kk][n0];
      float aa[4] = {a.x,a.y,a.z,a.w};
      float bb[4] = {b.x,b.y,b.z,b.w};
      #pragma unroll
      for (int i = 0; i < 4; ++i)
        #pragma unroll
        for (int j = 0; j < 4; ++j)
          acc[i][j] += aa[i]*bb[j];
    }
  }
  float4 badd = make_float4(0.f,0.f,0.f,0.f);
  if (bias) badd = *(const float4*)(bias + col0 + n0);
  #pragma unroll
  for (int i = 0; i < 4; ++i){
    int gr = row0 + m0 + i;
    if (gr < M){
      float4 r = make_float4(acc[i][0]+badd.x, acc[i][1]+badd.y, acc[i][2]+badd.z, acc[i][3]+badd.w);
      *(float4*)(C + (size_t)gr*N + col0 + n0) = r;
      if (obf) *(float4*)(obf + (size_t)gr*N + col0 + n0) = r;
    }
  }
}

// ---------------- MFMA flash attention (split-bf16, fp32 softmax), XCD-swizzled grid --------
__global__ __launch_bounds__(256)
void fattn_k(const ushort* __restrict__ Xh, const ushort* __restrict__ Xl,
             ushort* __restrict__ oh, ushort* __restrict__ ol)
{
  __shared__ ushort Kh[64][72], Kl[64][72];
  __shared__ ushort Vth[64][72], Vtl[64][72];
  __shared__ ushort Ph[64][72], Pl[64][72];
  int flat = blockIdx.x + (blockIdx.y << 2);
  int wgt = xcd_swz(flat, 4*256);
  int qt = wgt & 3, bh = wgt >> 2;   // same-bh q-tiles colocate on one XCD (K/V L2 reuse)
  int b = bh >> 3, h = bh & 7;
  int tid = threadIdx.x;
  int w = tid >> 6, lane = tid & 63;
  int fr = lane & 15, fu = lane >> 4;
  int qrow_f = qt*64 + w*16 + fr;
  int qtok = b*TT + (qrow_f < TT ? qrow_f : TT-1);
  const ushort* qph = Xh + (size_t)qtok*1536 + h*64 + fu*8;
  const ushort* qpl = Xl + (size_t)qtok*1536 + h*64 + fu*8;
  bf16x8 qh0 = *(const bf16x8*)(qph);
  bf16x8 qh1 = *(const bf16x8*)(qph + 32);
  bf16x8 ql0 = *(const bf16x8*)(qpl);
  bf16x8 ql1 = *(const bf16x8*)(qpl + 32);
  f32x4 o_acc[4] = {};
  float m_i[4], l_i[4];
  #pragma unroll
  for (int q = 0; q < 4; ++q){ m_i[q] = -3e38f; l_i[q] = 0.f; }
  int sr = tid >> 2, sc = (tid & 3) << 4;
  int ktiles = qt + 1;
  for (int kt = 0; kt < ktiles; ++kt){
    __syncthreads();
    {
      int jrow = kt*64 + sr;
      int jtok = b*TT + (jrow < TT ? jrow : TT-1);
      const ushort* kph = Xh + (size_t)jtok*1536 + 512 + h*64 + sc;
      const ushort* kpl = Xl + (size_t)jtok*1536 + 512 + h*64 + sc;
      *(uint4*)&Kh[sr][sc]   = *(const uint4*)kph;
      *(uint4*)&Kh[sr][sc+8] = *(const uint4*)(kph + 8);
      *(uint4*)&Kl[sr][sc]   = *(const uint4*)kpl;
      *(uint4*)&Kl[sr][sc+8] = *(const uint4*)(kpl + 8);
      const ushort* vph = Xh + (size_t)jtok*1536 + 1024 + h*64 + sc;
      const ushort* vpl = Xl + (size_t)jtok*1536 + 1024 + h*64 + sc;
      ushort tv[16];
      *(uint4*)&tv[0] = *(const uint4*)vph;
      *(uint4*)&tv[8] = *(const uint4*)(vph + 8);
      #pragma unroll
      for (int t = 0; t < 16; ++t) Vth[sc + t][sr] = tv[t];
      *(uint4*)&tv[0] = *(const uint4*)vpl;
      *(uint4*)&tv[8] = *(const uint4*)(vpl + 8);
      #pragma unroll
      for (int t = 0; t < 16; ++t) Vtl[sc + t][sr] = tv[t];
    }
    __syncthreads();
    f32x4 sacc[4] = {};
    #pragma unroll
    for (int j = 0; j < 4; ++j){
      bf16x8 kh0 = *(const bf16x8*)&Kh[j*16 + fr][fu*8];
      bf16x8 kh1 = *(const bf16x8*)&Kh[j*16 + fr][32 + fu*8];
      bf16x8 kl0 = *(const bf16x8*)&Kl[j*16 + fr][fu*8];
      bf16x8 kl1 = *(const bf16x8*)&Kl[j*16 + fr][32 + fu*8];
      sacc[j] = __builtin_amdgcn_mfma_f32_16x16x32_bf16(qh0, kh0, sacc[j], 0, 0, 0);
      sacc[j] = __builtin_amdgcn_mfma_f32_16x16x32_bf16(ql0, kh0, sacc[j], 0, 0, 0);
      sacc[j] = __builtin_amdgcn_mfma_f32_16x16x32_bf16(qh0, kl0, sacc[j], 0, 0, 0);
      sacc[j] = __builtin_amdgcn_mfma_f32_16x16x32_bf16(qh1, kh1, sacc[j], 0, 0, 0);
      sacc[j] = __builtin_amdgcn_mfma_f32_16x16x32_bf16(ql1, kh1, sacc[j], 0, 0, 0);
      sacc[j] = __builtin_amdgcn_mfma_f32_16x16x32_bf16(qh1, kl1, sacc[j], 0, 0, 0);
    }
    int rbase = qt*64 + w*16 + (fu<<2);
    int cg = kt*64 + fr;
    float p[4][4];
    #pragma unroll
    for (int q = 0; q < 4; ++q){
      int rg = rbase + q;
      float sv[4];
      #pragma unroll
      for (int j = 0; j < 4; ++j){
        int cj = cg + j*16;
        sv[j] = (cj <= rg && cj < TT) ? sacc[j][q]*0.125f : -3e38f;
      }
      float mx = fmaxf(fmaxf(sv[0],sv[1]), fmaxf(sv[2],sv[3]));
      #pragma unroll
      for (int off = 1; off < 16; off <<= 1) mx = fmaxf(mx, __shfl_xor(mx, off, 64));
      float mnew = fmaxf(m_i[q], mx);
      float al = expf(m_i[q] - mnew);
      l_i[q] *= al;
      o_acc[0][q] *= al; o_acc[1][q] *= al; o_acc[2][q] *= al; o_acc[3][q] *= al;
      float ps = 0.f;
      #pragma unroll
      for (int j = 0; j < 4; ++j){ p[q][j] = expf(sv[j] - mnew); ps += p[q][j]; }
      #pragma unroll
      for (int off = 1; off < 16; off <<= 1) ps += __shfl_xor(ps, off, 64);
      l_i[q] += ps;
      m_i[q] = mnew;
    }
    #pragma unroll
    for (int q = 0; q < 4; ++q){
      int pr = w*16 + (fu<<2) + q;
      #pragma unroll
      for (int j = 0; j < 4; ++j){
        ushort hu, lu; splitbf(p[q][j], hu, lu);
        Ph[pr][j*16 + fr] = hu;
        Pl[pr][j*16 + fr] = lu;
      }
    }
    bf16x8 ph0 = *(const bf16x8*)&Ph[w*16 + fr][fu*8];
    bf16x8 ph1 = *(const bf16x8*)&Ph[w*16 + fr][32 + fu*8];
    bf16x8 pl0 = *(const bf16x8*)&Pl[w*16 + fr][fu*8];
    bf16x8 pl1 = *(const bf16x8*)&Pl[w*16 + fr][32 + fu*8];
    #pragma unroll
    for (int jd = 0; jd < 4; ++jd){
      bf16x8 vh0 = *(const bf16x8*)&Vth[jd*16 + fr][fu*8];
      bf16x8 vh1 = *(const bf16x8*)&Vth[jd*16 + fr][32 + fu*8];
      bf16x8 vl0 = *(const bf16x8*)&Vtl[jd*16 + fr][fu*8];
      bf16x8 vl1 = *(const bf16x8*)&Vtl[jd*16 + fr][32 + fu*8];
      o_acc[jd] = __builtin_amdgcn_mfma_f32_16x16x32_bf16(ph0, vh0, o_acc[jd], 0, 0, 0);
      o_acc[jd] = __builtin_amdgcn_mfma_f32_16x16x32_bf16(pl0, vh0, o_acc[jd], 0, 0, 0);
      o_acc[jd] = __builtin_amdgcn_mfma_f32_16x16x32_bf16(ph0, vl0, o_acc[jd], 0, 0, 0);
      o_acc[jd] = __builtin_amdgcn_mfma_f32_16x16x32_bf16(ph1, vh1, o_acc[jd], 0, 0, 0);
      o_acc[jd] = __builtin_amdgcn_mfma_f32_16x16x32_bf16(pl1, vh1, o_acc[jd], 0, 0, 0);
      o_acc[jd] = __builtin_amdgcn_mfma_f32_16x16x32_bf16(ph1, vl1, o_acc[jd], 0, 0, 0);
    }
  }
  #pragma unroll
  for (int q = 0; q < 4; ++q){
    int rg = qt*64 + w*16 + (fu<<2) + q;
    if (rg < TT){
      float inv = 1.f / l_i[q];
      size_t rowoff = (size_t)(b*TT + rg)*DM + h*64 + fr;
      #pragma unroll
      for (int jd = 0; jd < 4; ++jd){
        float v = o_acc[jd][q] * inv;
        ushort hu, lu; splitbf(v, hu, lu);
        oh[rowoff + jd*16] = hu;
        ol[rowoff + jd*16] = lu;
      }
    }
  }
}

// ---------------- router: reads split-bf16 X pair; LDS-staged transposed weights ----------------
__global__ __launch_bounds__(256)
void router2_k(const ushort* __restrict__ Xh, const ushort* __restrict__ Xl,
               const float* __restrict__ rtW, const float* __restrict__ rtb,
               const float* __restrict__ rnW, const float* __restrict__ rnb, const float* __restrict__ nz,
               int* __restrict__ tok_e, float* __restrict__ tok_g)
{
  __shared__ float Wt[8*513];
  __shared__ float Wn[8*513];
  int tid = threadIdx.x;
  for (int i = tid*4; i < DM*8; i += 1024){
    float4 t = *(const float4*)(rtW + i);
    float4 n = *(const float4*)(rnW + i);
    int d = i >> 3, e = i & 7;
    Wt[(e+0)*513 + d] = t.x; Wt[(e+1)*513 + d] = t.y; Wt[(e+2)*513 + d] = t.z; Wt[(e+3)*513 + d] = t.w;
    Wn[(e+0)*513 + d] = n.x; Wn[(e+1)*513 + d] = n.y; Wn[(e+2)*513 + d] = n.z; Wn[(e+3)*513 + d] = n.w;
  }
  __syncthreads();
  int w = tid >> 6, lane = tid & 63;
  int t = (blockIdx.x << 2) + w;
  const ushort* xh = Xh + (size_t)t * DM;
  const ushort* xl = Xl + (size_t)t * DM;
  float at[8] = {}, an[8] = {};
  #pragma unroll
  for (int u = 0; u < 8; ++u){
    int d = (u<<6) + lane;
    float xv = bf2f(xh[d]) + bf2f(xl[d]);
    #pragma unroll
    for (int e = 0; e < 8; ++e){
      at[e] += xv * Wt[e*513 + d];
      an[e] += xv * Wn[e*513 + d];
    }
  }
  #pragma unroll
  for (int off = 32; off; off >>= 1){
    #pragma unroll
    for (int e = 0; e < 8; ++e){
      at[e] += __shfl_xor(at[e], off, 64);
      an[e] += __shfl_xor(an[e], off, 64);
    }
  }
  if (lane == 0){
    float ns[8];
    #pragma unroll
    for (int e = 0; e < 8; ++e){
      float lt = at[e] + rtb[e];
      float ln_ = an[e] + rnb[e];
      float sp = (ln_ > 0.f) ? (ln_ + log1pf(expf(-ln_))) : log1pf(expf(ln_));
      ns[e] = lt + nz[(size_t)t*8 + e] * sp;
    }
    int i1 = 0; float n1 = ns[0];
    #pragma unroll
    for (int e = 1; e < 8; ++e) if (ns[e] > n1){ n1 = ns[e]; i1 = e; }
    int i2 = -1; float n2 = -3e38f;
    #pragma unroll
    for (int e = 0; e < 8; ++e) if (e != i1 && ns[e] > n2){ n2 = ns[e]; i2 = e; }
    float ex = expf(n2 - n1);
    float inv = 1.f / (1.f + ex);
    tok_e[t*2]   = i1; tok_g[t*2]   = inv;
    tok_e[t*2+1] = i2; tok_g[t*2+1] = ex * inv;
  }
}

// ------- histogram + prefix + slot assignment, wave-ballot aggregated -------
__global__ __launch_bounds__(1024)
void route_assign_k(const int* __restrict__ tok_e, int* __restrict__ offs_g,
                    int* __restrict__ idx_c, int* __restrict__ tok_slot)
{
  __shared__ int hist[NE];
  __shared__ int cur[NE];
  int tid = threadIdx.x;
  int lane = tid & 63;
  if (tid < NE) hist[tid] = 0;
  __syncthreads();
  for (int i = tid; i < BT*2; i += 1024){
    int e = tok_e[i];
    #pragma unroll
    for (int x = 0; x < NE; ++x){
      unsigned long long m = __ballot(e == x);
      if (m && lane == (int)__builtin_ctzll(m)) atomicAdd(&hist[x], __popcll(m));
    }
  }
  __syncthreads();
  if (tid == 0){
    int s = 0;
    for (int e = 0; e < NE; ++e){ offs_g[e] = s; cur[e] = s; s += hist[e]; }
    offs_g[NE] = s;
  }
  __syncthreads();
  for (int i = tid; i < BT*2; i += 1024){
    int e = tok_e[i];
    int p = 0;
    #pragma unroll
    for (int x = 0; x < NE; ++x){
      unsigned long long m = __ballot(e == x);
      if (m){
        int leader = (int)__builtin_ctzll(m);
        int bw = 0;
        if (lane == leader) bw = atomicAdd(&cur[x], __popcll(m));
        bw = __shfl(bw, leader, 64);
        if (e == x) p = bw + __popcll(m & ((lane == 63) ? 0x7fffffffffffffffull : ((1ull << lane) - 1ull)));
      }
    }
    idx_c[p] = i >> 1;
    tok_slot[i] = p;
  }
}

// ---------------- fused expert-weight transpose+convert: eWi and eWo in one launch ----------
__global__ __launch_bounds__(256)
void transconv2_k(const float* __restrict__ eWi, const float* __restrict__ eWo,
                  ushort* __restrict__ WiT, ushort* __restrict__ WoT){
  __shared__ float t[32][33];
  int z = blockIdx.z;
  const float* src; ushort* dst; int R, C, c0, r0;
  if (z < NE){
    src = eWi + (size_t)z*DM*FFD; dst = WiT + (size_t)z*DM*FFD;
    R = DM; C = FFD; c0 = blockIdx.x << 5; r0 = blockIdx.y << 5;
  } else {
    int e = z - NE;
    src = eWo + (size_t)e*FFD*DM; dst = WoT + (size_t)e*FFD*DM;
    R = FFD; C = DM; c0 = blockIdx.y << 5; r0 = blockIdx.x << 5;
  }
  int tx = threadIdx.x & 31, ty = threadIdx.x >> 5;
  #pragma unroll
  for (int i = 0; i < 32; i += 8)
    t[ty+i][tx] = src[(size_t)(r0+ty+i)*C + c0 + tx];
  __syncthreads();
  #pragma unroll
  for (int i = 0; i < 32; i += 8)
    dst[(size_t)(c0+ty+i)*R + r0 + tx] = f2bf(t[tx][ty+i]);
}

// ---------------- MoE expert GEMM, bf16 MFMA, counted-vmcnt 2-deep, XCD swizzle ------------
// MODE 0: A rows gathered via aidx (idx_c); bounce-epilogue bf16 out. grid (fcw/128, 49, NE)
// MODE 1: slot-space rows; fp32 out. nks=2: grid (8,49,NE), bx>>2 = K-half, out buffer +kh*SLOTS*DM.
template<int MODE>
__global__ __launch_bounds__(256)
void moe_mfma(const ushort* __restrict__ A, const int* __restrict__ aidx,
              const ushort* __restrict__ Bt,
              const float* __restrict__ bias, const int* __restrict__ offs,
              void* __restrict__ Out, int kld, int ldb, int out_ld,
              int klen, int accum, int nks)
{
  __shared__ __align__(16) ushort smem[2][2*128*32];
  ushort* As = smem[0];
  ushort* Bs = smem[1];
  int gx = gridDim.x, gy = gridDim.y;
  int nwg = gx * gy * (int)gridDim.z;
  int fblk = blockIdx.x + gx*(blockIdx.y + gy*blockIdx.z);
  int wgt = xcd_swz(fblk, nwg);
  int bx = wgt % gx; wgt /= gx;
  int by = wgt % gy; int bz = wgt / gy;
  int kh = 0;
  if (MODE == 1 && nks == 2){ kh = bx >> 2; bx &= 3; }
  int e = bz;
  int base = offs[e], cnt = offs[e+1] - base;
  int row0 = by << 7;
  if (row0 >= cnt) return;
  int col0 = bx << 7;
  size_t kofs = (size_t)kh * klen;
  int tid = threadIdx.x, lane = tid & 63, w = tid >> 6;
  int wr = w >> 1, wc = w & 1;
  int fr = lane & 15, fu = lane >> 4;
  int srow = 16*w + (lane >> 2);
  int cs = ((lane & 3) ^ ((srow >> 1) & 3)) << 3;
  int s0 = base + row0 + srow;      if (s0 > SLOTS-1) s0 = SLOTS-1;
  int s1 = base + row0 + 64 + srow; if (s1 > SLOTS-1) s1 = SLOTS-1;
  int r0i = (MODE == 0) ? aidx[s0] : s0;
  int r1i = (MODE == 0) ? aidx[s1] : s1;
  const ushort* gA0 = A + (size_t)r0i * kld + kofs + cs;
  const ushort* gA1 = A + (size_t)r1i * kld + kofs + cs;
  const ushort* Bb = Bt + (size_t)e * ((size_t)FFD*DM);
  const ushort* gB0 = Bb + (size_t)(col0 + srow) * ldb + kofs + cs;
  const ushort* gB1 = Bb + (size_t)(col0 + 64 + srow) * ldb + kofs + cs;
  int lo0 = (16*w)*32, lo1 = (64+16*w)*32;
  #define MSTAGE(koff, nb) { \
    glds16(gA0 + (koff), &As[(nb)+lo0]); glds16(gA1 + (koff), &As[(nb)+lo1]); \
    glds16(gB0 + (koff), &Bs[(nb)+lo0]); glds16(gB1 + (koff), &Bs[(nb)+lo1]); }
  f32x4 acc[4][4] = {};
  int nt = klen >> 5;
  MSTAGE(0, 0)
  MSTAGE(32, 128*32)
  for (int t = 0; t < nt; ++t){
    if (t + 1 < nt) asm volatile("s_waitcnt vmcnt(4)" ::: "memory");
    else            asm volatile("s_waitcnt vmcnt(0)" ::: "memory");
    __builtin_amdgcn_s_barrier();
    asm volatile("" ::: "memory");
    int cb = (t & 1) * (128*32);
    bf16x8 af[4], bf[4];
    #pragma unroll
    for (int i = 0; i < 4; ++i){
      int Ra = (wr<<6) + (i<<4) + fr;
      af[i] = *(const bf16x8*)&As[cb + Ra*32 + ((fu ^ ((Ra>>1)&3))<<3)];
      int Rb = (wc<<6) + (i<<4) + fr;
      bf[i] = *(const bf16x8*)&Bs[cb + Rb*32 + ((fu ^ ((Rb>>1)&3))<<3)];
    }
    #pragma unroll
    for (int i = 0; i < 4; ++i)
      #pragma unroll
      for (int j = 0; j < 4; ++j)
        acc[i][j] = __builtin_amdgcn_mfma_f32_16x16x32_bf16(af[i], bf[j], acc[i][j], 0, 0, 0);
    asm volatile("" ::: "memory");
    __builtin_amdgcn_s_barrier();
    if (t + 2 < nt) MSTAGE((t+2) << 5, (t & 1) * (128*32))
  }
  #undef MSTAGE
  int fq = lane >> 4;
  if (MODE == 0){
    // LDS-bounce epilogue: relu+bias -> bf16 tile in LDS (swizzled), flush full lines
    ushort* Ls = smem[0];   // 16384 ushorts = [128][128], spans both arrays
    __syncthreads();
    #pragma unroll
    for (int j = 0; j < 4; ++j){
      int lcol = (wc<<6) + (j<<4) + fr;
      float bv = bias[(size_t)e*FFD + col0 + lcol];
      #pragma unroll
      for (int i = 0; i < 4; ++i){
        #pragma unroll
        for (int q = 0; q < 4; ++q){
          int lrow = (wr<<6) + (i<<4) + (fq<<2) + q;
          float vv = acc[i][j][q] + bv;
          int g = (lrow >> 2) & 7;
          Ls[lrow*128 + ((((lcol>>3) ^ g))<<3) + (lcol & 7)] = f2bf(fmaxf(vv, 0.f));
        }
      }
    }
    __syncthreads();
    #pragma unroll
    for (int pass = 0; pass < 8; ++pass){
      int lrow = pass*16 + (tid >> 4);
      int s = tid & 15;
      int g = (lrow >> 2) & 7;
      uint4 v = *(const uint4*)&Ls[lrow*128 + ((s ^ g)<<3)];
      int gr = row0 + lrow;
      if (gr < cnt)
        *(uint4*)&((ushort*)Out)[(size_t)(base+gr)*out_ld + col0 + s*8] = v;
    }
  } else {
    float* Yb = (float*)Out + (size_t)kh * ((size_t)SLOTS * DM);
    #pragma unroll
    for (int j = 0; j < 4; ++j){
      int col = col0 + (wc<<6) + (j<<4) + fr;
      float bv = (kh == 0) ? bias[(size_t)e*DM + col] : 0.f;
      #pragma unroll
      for (int i = 0; i < 4; ++i){
        #pragma unroll
        for (int q = 0; q < 4; ++q){
          int rr = row0 + (wr<<6) + (i<<4) + (fq<<2) + q;
          if (rr < cnt){
            float* yp = Yb + (size_t)(base+rr)*out_ld + col;
            if (nks == 2) *yp = acc[i][j][q] + bv;
            else          *yp = acc[i][j][q] + (accum ? *yp : bv);
          }
        }
      }
    }
  }
}

// ---------------- gated combine (optionally 2 split-K partials) + layernorm -> split-bf16 ----
__global__ __launch_bounds__(256)
void combine_ln_k(const float* __restrict__ Ye, const float* __restrict__ Ye2,
                  const int* __restrict__ tok_slot,
                  const float* __restrict__ tok_g, const float* __restrict__ g,
                  const float* __restrict__ bb, ushort* __restrict__ oh, ushort* __restrict__ ol)
{
  int t = blockIdx.x, tid = threadIdx.x;
  int s1 = tok_slot[t*2], s2 = tok_slot[t*2+1];
  float g1 = tok_g[t*2], g2 = tok_g[t*2+1];
  const float* y1 = Ye + (size_t)s1*DM;
  const float* y2 = Ye + (size_t)s2*DM;
  float a0 = y1[tid],      a1 = y1[tid+256];
  float b0 = y2[tid],      b1 = y2[tid+256];
  if (Ye2){
    const float* z1 = Ye2 + (size_t)s1*DM;
    const float* z2 = Ye2 + (size_t)s2*DM;
    a0 += z1[tid]; a1 += z1[tid+256];
    b0 += z2[tid]; b1 += z2[tid+256];
  }
  float v0 = g1*a0 + g2*b0;
  float v1 = g1*a1 + g2*b1;
  __shared__ float red[8];
  int w = tid >> 6, lane = tid & 63;
  float s = v0 + v1;
  #pragma unroll
  for (int off = 32; off; off >>= 1) s += __shfl_xor(s, off, 64);
  if (lane == 0) red[w] = s;
  __syncthreads();
  float mu = (red[0]+red[1]+red[2]+red[3]) * (1.f/512.f);
  float d0 = v0 - mu, d1 = v1 - mu;
  float q2 = d0*d0 + d1*d1;
  #pragma unroll
  for (int off = 32; off; off >>= 1) q2 += __shfl_xor(q2, off, 64);
  if (lane == 0) red[4+w] = q2;
  __syncthreads();
  float var = (red[4]+red[5]+red[6]+red[7]) * (1.f/512.f);
  float r = 1.f / sqrtf(var + 1e-5f);
  float r0v = d0*r*g[tid]     + bb[tid];
  float r1v = d1*r*g[tid+256] + bb[tid+256];
  ushort hu, lu;
  splitbf(r0v, hu, lu);
  oh[(size_t)t*DM + tid] = hu; ol[(size_t)t*DM + tid] = lu;
  splitbf(r1v, hu, lu);
  oh[(size_t)t*DM + tid + 256] = hu; ol[(size_t)t*DM + tid + 256] = lu;
}

// ---------------- global = sum over T of second_vector ----------------
__global__ void gsum_k(const float* __restrict__ sv, float* __restrict__ gb, float* __restrict__ gout){
  int i = blockIdx.x*256 + threadIdx.x;
  int b = i >> 9, d = i & 511;
  const float* p = sv + (size_t)b*TT*DM + d;
  float s = 0.f;
  for (int t = 0; t < TT; ++t) s += p[(size_t)t*DM];
  gb[i] = s; gout[i] = s;
}

extern "C" void kernel_launch(void* const* d_in, const int* in_sizes, int n_in,
                              void* d_out, int out_size, void* d_ws, size_t ws_size,
                              hipStream_t stream)
{
  (void)in_sizes; (void)n_in; (void)out_size;
  const float* xin   = (const float*)d_in[0];
  const float* pembW = (const float*)d_in[1];
  const float* pembB = (const float*)d_in[2];
  const float* vecW  = (const float*)d_in[3];
  const float* vecB  = (const float*)d_in[4];
  const float* clsW  = (const float*)d_in[5];
  const float* clsB  = (const float*)d_in[6];
  float* out = (float*)d_out;

  // ---- workspace budget (floats). FoldW/PW live inside the QKV/H1 region. ----
  const size_t QKV_SH  = (size_t)2*BT*1536;
  const size_t RMIN_SH = QKV_SH + (size_t)2*1536*DM + (size_t)2*DM*DM;   // + FoldW pair + PW pair
  const size_t FIXF =
      (size_t)SLOTS*DM                         // Yexp fp32
    + (size_t)2*ABUF                           // S0/S1 split pairs (4*ABUF shorts)
    + (size_t)NE*FFD*DM                        // WiT+WoT shorts
    + (size_t)256*DM                           // Pemb pair shorts->floats
    + (size_t)DM*DM                            // Vec pair
    + (size_t)3*DM*DM                          // QkvW pair
    + (size_t)DM*DM                            // WoS pair
    + (size_t)TT*DM + 2048                     // posenc + bfold
    + 16384*2 + SLOTS + SLOTS*3 + 256;
  // try split-K2 (needs Yexp2) with fcw=2048; else fallback ladder (no split)
  int fcw = 256, ksplit = 1;
  {
    size_t reg_sh = (size_t)SLOTS*2048 > RMIN_SH ? (size_t)SLOTS*2048 : RMIN_SH;
    size_t need2 = (FIXF + (size_t)SLOTS*DM + reg_sh/2) * sizeof(float);
    if (need2 <= ws_size){ ksplit = 2; fcw = 2048; }
    else {
      for (int cand = 2048; cand >= 256; cand >>= 1){
        size_t rs = (size_t)SLOTS*cand > RMIN_SH ? (size_t)SLOTS*cand : RMIN_SH;
        size_t need = (FIXF + rs/2) * sizeof(float);
        if (need <= ws_size){ fcw = cand; break; }
      }
    }
  }
  size_t region_sh = (size_t)SLOTS*fcw > RMIN_SH ? (size_t)SLOTS*fcw : RMIN_SH;
  size_t yex2f = (ksplit == 2) ? (size_t)SLOTS*DM : 0;

  float* ws = (float*)d_ws;
  float* Yexp  = ws;
  float* Yexp2 = ws + (size_t)SLOTS*DM;            // valid only when ksplit==2
  ushort* S0h = (ushort*)(Yexp + (size_t)SLOTS*DM + yex2f);
  ushort* S0l = S0h + ABUF;
  ushort* S1h = S0l + ABUF;
  ushort* S1l = S1h + ABUF;
  ushort* region = S1l + ABUF;
  ushort* WiT  = region + region_sh;
  ushort* WoT  = WiT + (size_t)NE*FFD*DM;
  ushort* PembH = WoT + (size_t)NE*FFD*DM;
  ushort* PembL = PembH + 256*DM;
  ushort* VecH = PembL + 256*DM;
  ushort* VecL = VecH + DM*DM;
  ushort* QkvWH = VecL + DM*DM;
  ushort* QkvWL = QkvWH + 3*DM*DM;
  ushort* WoSH = QkvWL + 3*DM*DM;
  ushort* WoSL = WoSH + DM*DM;
  float* pe    = (float*)(WoSL + DM*DM);
  float* bfold = pe + TT*DM;
  float* gbv   = bfold + 2048;
  float* clsbuf= gbv + 16384;
  float* tok_g = clsbuf + 16384;
  int* tok_e   = (int*)(tok_g + SLOTS);
  int* tok_slot= tok_e + SLOTS;
  int* idx_c   = tok_slot + SLOTS;
  int* offs    = idx_c + SLOTS;      // 9 ints
  // region internals (time-multiplexed)
  ushort* QKVh = region;
  ushort* QKVl = region + (size_t)BT*1536;
  ushort* FoldWH = region + QKV_SH;
  ushort* FoldWL = FoldWH + (size_t)1536*DM;
  ushort* PWh  = FoldWL + (size_t)1536*DM;
  ushort* PWl  = PWh + (size_t)DM*DM;
  ushort* H1b  = region;
  ushort* PATh = region;
  ushort* PATl = region + (size_t)BT*256;

  patchify_k<<<dim3(BT), dim3(256), 0, stream>>>(xin, PATh, PATl);
  posenc_k<<<dim3(TT), dim3(512), 0, stream>>>(pe);
  wsplit_k<<<dim3(16, 8), dim3(256), 0, stream>>>(pembW, PembH, PembL, 256, DM);
  wsplit_k<<<dim3(16, 16), dim3(256), 0, stream>>>(vecW, VecH, VecL, DM, DM);
  // h = patches @ pembW + b + posenc -> split S0
  gemm_s<<<dim3(4,49), dim3(256), 0, stream>>>(PATh, PATl, PembH, PembL, pembB, pe,
                                               nullptr, S0h, S0l, DM, 256);

  ushort *INh = S0h, *INl = S0l, *TPh = S1h, *TPl = S1l;
  for (int l = 0; l < 2; ++l){
    int base = 7 + 18*l;
    const float* pW  = (const float*)d_in[base+0];
    const float* pb  = (const float*)d_in[base+1];
    const float* Wq  = (const float*)d_in[base+2];
    const float* Wk  = (const float*)d_in[base+3];
    const float* Wv  = (const float*)d_in[base+4];
    const float* Wo  = (const float*)d_in[base+5];
    const float* bo  = (const float*)d_in[base+6];
    const float* rtW = (const float*)d_in[base+7];
    const float* rtb = (const float*)d_in[base+8];
    const float* rnW = (const float*)d_in[base+9];
    const float* rnb = (const float*)d_in[base+10];
    const float* eWi = (const float*)d_in[base+11];
    const float* ebi = (const float*)d_in[base+12];
    const float* eWo = (const float*)d_in[base+13];
    const float* ebo = (const float*)d_in[base+14];
    const float* lng = (const float*)d_in[base+15];
    const float* lnb = (const float*)d_in[base+16];
    const float* nz  = (const float*)d_in[base+17];

    // dense attn weights (Qkv^T, Wo^T) + pW elementwise split, one launch
    wsplit5e_k<<<dim3(16,16,5), dim3(256), 0, stream>>>(Wq, Wk, Wv, Wo, pW,
                                                        QkvWH, QkvWL, WoSH, WoSL, PWh, PWl);
    // fold in-projection into QKV: FoldW[m][i] = sum_d Wqkv^T[m][d] * pW[i][d]
    gemm_s<<<dim3(4,12), dim3(256), 0, stream>>>(QkvWH, QkvWL, PWh, PWl, nullptr, nullptr,
                                                 nullptr, FoldWH, FoldWL, DM, DM);
    bfold_k<<<dim3(384), dim3(256), 0, stream>>>(pb, Wq, Wk, Wv, bfold);
    // QKV = IN @ FoldW^T + bfold  (split pair [BT][1536])
    gemm_s<<<dim3(12,49), dim3(256), 0, stream>>>(INh, INl, FoldWH, FoldWL, bfold, nullptr,
                                                 nullptr, QKVh, QKVl, 1536, DM);
    // attention: QKV -> IN (split)
    fattn_k<<<dim3(4,256), dim3(256), 0, stream>>>(QKVh, QKVl, INh, INl);
    // output projection: IN -> TP (router + MoE input)
    gemm_s<<<dim3(4,49), dim3(256), 0, stream>>>(INh, INl, WoSH, WoSL, bo, nullptr,
                                                 nullptr, TPh, TPl, DM, DM);
    // expert weights -> bf16 transposed (single fused launch)
    transconv2_k<<<dim3(64, 16, 2*NE), dim3(256), 0, stream>>>(eWi, eWo, WiT, WoT);
    // routing
    router2_k<<<dim3(BT/4), dim3(256), 0, stream>>>(TPh, TPl, rtW, rtb, rnW, rnb, nz, tok_e, tok_g);
    route_assign_k<<<dim3(1), dim3(1024), 0, stream>>>(tok_e, offs, idx_c, tok_slot);
    // experts (QKV/FoldW region dead now; H1b aliases it); A gathered directly via idx_c
    if (ksplit == 2){
      moe_mfma<0><<<dim3(16, 49, NE), dim3(256), 0, stream>>>(
          TPh, idx_c, WiT, ebi, offs, (void*)H1b, DM, DM, 2048, 512, 0, 1);
      moe_mfma<1><<<dim3(8, 49, NE), dim3(256), 0, stream>>>(
          H1b, nullptr, WoT, ebo, offs, (void*)Yexp, 2048, FFD, DM, 1024, 0, 2);
    } else {
      for (int c0 = 0; c0 < FFD; c0 += fcw){
        moe_mfma<0><<<dim3(fcw/128, 49, NE), dim3(256), 0, stream>>>(
            TPh, idx_c, WiT + (size_t)c0*DM, ebi + c0, offs, (void*)H1b, DM, DM, fcw, 512, 0, 1);
        moe_mfma<1><<<dim3(DM/128, 49, NE), dim3(256), 0, stream>>>(
            H1b, nullptr, WoT + c0, ebo, offs, (void*)Yexp, fcw, FFD, DM, fcw, c0, 1);
      }
    }
    // combine + LN -> IN (split)
    combine_ln_k<<<dim3(BT), dim3(256), 0, stream>>>(Yexp, (ksplit == 2) ? Yexp2 : nullptr,
                                                     tok_slot, tok_g, lng, lnb, INh, INl);
    // vector projection: IN -> out mirror (fp32) + TP (next layer input, split)
    gemm_s<<<dim3(4,49), dim3(256), 0, stream>>>(INh, INl, VecH, VecL, vecB, nullptr,
                                                 out + (size_t)l*ABUF, TPh, TPl, DM, DM);
    ushort* th = INh; INh = TPh; TPh = th;
    ushort* tl = INl; INl = TPl; TPl = tl;
  }

  gsum_k<<<dim3(64), dim3(256), 0, stream>>>(out + ABUF, gbv, out + 2*ABUF);
  gemm_f32<<<dim3(8,1), dim3(256), 0, stream>>>(gbv, clsW, clsbuf, clsB, out + 2*ABUF + 16384, 32, DM, DM);
}

// Round 10
// 939.074 us; speedup vs baseline: 1.0221x; 1.0221x over previous
//
#include <hip/hip_runtime.h>

#define BT 6272      // B*T = 32*196
#define TT 196
#define DM 512
#define FFD 2048
#define NE 8
#define ABUF 3211264 // activation buffer elems (6272*512)
#define SLOTS 12544  // BT*2 expert slots

typedef float f32x4 __attribute__((ext_vector_type(4)));
typedef __bf16 bf16x8 __attribute__((ext_vector_type(8)));

__device__ __forceinline__ ushort f2bf(float f){
  union { float f; unsigned u; } v; v.f = f;
  unsigned u = v.u;
  u += 0x7fffu + ((u >> 16) & 1u);   // RNE
  return (ushort)(u >> 16);
}
__device__ __forceinline__ float bf2f(ushort u){
  union { unsigned u; float f; } c; c.u = ((unsigned)u) << 16; return c.f;
}
// split fp32 into bf16 hi (truncated) + bf16 lo (RNE of remainder): a ~= hi + lo, err ~2^-17
__device__ __forceinline__ void splitbf(float v, ushort& hi, ushort& lo){
  union { float f; unsigned u; } c; c.f = v;
  hi = (ushort)(c.u >> 16);
  union { unsigned u; float f; } hf; hf.u = c.u & 0xffff0000u;
  lo = f2bf(v - hf.f);
}
// async global->LDS 16B: lds dest is wave-uniform base (lane writes base+lane*16)
__device__ __forceinline__ void glds16(const ushort* g, ushort* l){
  __builtin_amdgcn_global_load_lds(
      (const __attribute__((address_space(1))) unsigned int*)g,
      (__attribute__((address_space(3))) unsigned int*)l, 16, 0, 0);
}
// bijective XCD-chunked block remap (m204): contiguous work per XCD
__device__ __forceinline__ int xcd_swz(int f, int nwg){
  int q = nwg >> 3, r = nwg & 7;
  int xcd = f & 7, i = f >> 3;
  return (xcd < r ? xcd*(q+1) : r*(q+1) + (xcd-r)*q) + i;
}

// ---------------- patchify: x[B,1,224,224] f32 -> split-bf16 patches[BT,256] ----------------
__global__ void patchify_k(const float* __restrict__ x, ushort* __restrict__ oh, ushort* __restrict__ ol){
  int bt = blockIdx.x;
  int t = bt % TT, b = bt / TT;
  int pd = threadIdx.x;
  int g1 = t / 14, g2 = t % 14, p1 = pd >> 4, p2 = pd & 15;
  int src = (b*224 + g1*16 + p1)*224 + g2*16 + p2;
  float v = x[src];
  ushort hu, lu; splitbf(v, hu, lu);
  oh[(size_t)bt*256 + pd] = hu;
  ol[(size_t)bt*256 + pd] = lu;
}

// ---------------- posenc[196,512] f32 ----------------
__global__ void posenc_k(float* __restrict__ pe){
  int t = blockIdx.x, c = threadIdx.x;
  int m2 = c & ~1;
  double ang = (double)t * pow(10000.0, -(double)m2 / 512.0);
  double vv = (c & 1) ? cos(ang) : sin(ang);
  pe[t*DM + c] = (float)vv;
}

// ---------------- weight transpose + split: src[R][C] f32 -> dh/dl[C][R] bf16 hi/lo ----------------
__global__ __launch_bounds__(256)
void wsplit_k(const float* __restrict__ src, ushort* __restrict__ dh, ushort* __restrict__ dl,
              int R, int C){
  __shared__ float t[32][33];
  int c0 = blockIdx.x << 5, r0 = blockIdx.y << 5;
  int tx = threadIdx.x & 31, ty = threadIdx.x >> 5;
  #pragma unroll
  for (int i = 0; i < 32; i += 8)
    t[ty+i][tx] = src[(size_t)(r0+ty+i)*C + c0 + tx];
  __syncthreads();
  #pragma unroll
  for (int i = 0; i < 32; i += 8){
    float v = t[tx][ty+i];
    ushort hu, lu; splitbf(v, hu, lu);
    dh[(size_t)(c0+ty+i)*R + r0 + tx] = hu;
    dl[(size_t)(c0+ty+i)*R + r0 + tx] = lu;
  }
}

// ------- batched 5-way: z=0..2 Wq/Wk/Wv transpose->QkvW; z=3 Wo transpose->WoS; z=4 pW elementwise ----
__global__ __launch_bounds__(256)
void wsplit5e_k(const float* __restrict__ s0, const float* __restrict__ s1,
                const float* __restrict__ s2, const float* __restrict__ s3,
                const float* __restrict__ s4,
                ushort* __restrict__ dQkvH, ushort* __restrict__ dQkvL,
                ushort* __restrict__ dWoH, ushort* __restrict__ dWoL,
                ushort* __restrict__ dPWh, ushort* __restrict__ dPWl)
{
  int z = blockIdx.z;
  int c0 = blockIdx.x << 5, r0 = blockIdx.y << 5;
  int tx = threadIdx.x & 31, ty = threadIdx.x >> 5;
  if (z == 4){   // elementwise split of pW (no transpose)
    #pragma unroll
    for (int i = 0; i < 32; i += 8){
      size_t idx = (size_t)(r0+ty+i)*DM + c0 + tx;
      ushort hu, lu; splitbf(s4[idx], hu, lu);
      dPWh[idx] = hu; dPWl[idx] = lu;
    }
    return;
  }
  const float* src = (z==0)? s0 : (z==1)? s1 : (z==2)? s2 : s3;
  ushort* dh; ushort* dl;
  if (z == 3){ dh = dWoH; dl = dWoL; }
  else { dh = dQkvH + (size_t)z*DM*DM; dl = dQkvL + (size_t)z*DM*DM; }
  __shared__ float t[32][33];
  #pragma unroll
  for (int i = 0; i < 32; i += 8)
    t[ty+i][tx] = src[(size_t)(r0+ty+i)*DM + c0 + tx];
  __syncthreads();
  #pragma unroll
  for (int i = 0; i < 32; i += 8){
    float v = t[tx][ty+i];
    ushort hu, lu; splitbf(v, hu, lu);
    dh[(size_t)(c0+ty+i)*DM + r0 + tx] = hu;
    dl[(size_t)(c0+ty+i)*DM + r0 + tx] = lu;
  }
}

// ---------------- folded QKV bias: bf[n] = sum_d pb[d] * Wqkv[d][n]; wave-per-n ----------
__global__ __launch_bounds__(256)
void bfold_k(const float* __restrict__ pb, const float* __restrict__ Wq,
             const float* __restrict__ Wk, const float* __restrict__ Wv,
             float* __restrict__ bf){
  int tid = threadIdx.x;
  int w = tid >> 6, lane = tid & 63;
  int n = blockIdx.x*4 + w;            // grid 384 -> n in [0,1536)
  const float* W = (n < 512) ? Wq : (n < 1024) ? Wk : Wv;
  int c = n & 511;
  float s = 0.f;
  #pragma unroll
  for (int u = 0; u < 8; ++u){
    int d = (u<<6) + lane;
    s += pb[d] * W[(size_t)d*DM + c];
  }
  #pragma unroll
  for (int off = 32; off; off >>= 1) s += __shfl_xor(s, off, 64);
  if (lane == 0) bf[n] = s;
}

// ---------------- dense split-bf16 MFMA GEMM, 128x128 tile, counted-vmcnt 2-deep pipeline --
// LDS bounce epilogue for split-bf16 outputs (full-line vectorized stores).
__global__ __launch_bounds__(256)
void gemm_s(const ushort* __restrict__ Ah, const ushort* __restrict__ Al,
            const ushort* __restrict__ Bh, const ushort* __restrict__ Bl,
            const float* __restrict__ bias, const float* __restrict__ pe,
            float* __restrict__ Cf, ushort* __restrict__ Ch, ushort* __restrict__ Cl,
            int N, int kld)
{
  __shared__ __align__(16) ushort smem[4][2*128*32];   // Ahs/Als/Bhs/Bls, 16KB each
  ushort* Ahs = smem[0];
  ushort* Als = smem[1];
  ushort* Bhs = smem[2];
  ushort* Bls = smem[3];
  int gx = gridDim.x, gy = gridDim.y;
  int fblk = blockIdx.x + gx*blockIdx.y;
  int wgt = xcd_swz(fblk, gx*gy);
  int bx = wgt % gx, by = wgt / gx;
  int row0 = by << 7, col0 = bx << 7;
  int tid = threadIdx.x;
  int lane = tid & 63, w = tid >> 6;
  int wr = w >> 1, wc = w & 1;
  int fr = lane & 15, fu = lane >> 4;
  int srow = 16*w + (lane >> 2);
  int cs = ((lane & 3) ^ ((srow >> 1) & 3)) << 3;   // pre-swizzled source chunk (shorts)
  const ushort* gAh0 = Ah + (size_t)(row0 + srow) * kld + cs;
  const ushort* gAh1 = Ah + (size_t)(row0 + 64 + srow) * kld + cs;
  const ushort* gAl0 = Al + (size_t)(row0 + srow) * kld + cs;
  const ushort* gAl1 = Al + (size_t)(row0 + 64 + srow) * kld + cs;
  const ushort* gBh0 = Bh + (size_t)(col0 + srow) * kld + cs;
  const ushort* gBh1 = Bh + (size_t)(col0 + 64 + srow) * kld + cs;
  const ushort* gBl0 = Bl + (size_t)(col0 + srow) * kld + cs;
  const ushort* gBl1 = Bl + (size_t)(col0 + 64 + srow) * kld + cs;
  int lo0 = (16*w)*32, lo1 = (64+16*w)*32;
  #define GSTAGE(koff, nb) { \
    glds16(gAh0 + (koff), &Ahs[(nb)+lo0]); glds16(gAh1 + (koff), &Ahs[(nb)+lo1]); \
    glds16(gAl0 + (koff), &Als[(nb)+lo0]); glds16(gAl1 + (koff), &Als[(nb)+lo1]); \
    glds16(gBh0 + (koff), &Bhs[(nb)+lo0]); glds16(gBh1 + (koff), &Bhs[(nb)+lo1]); \
    glds16(gBl0 + (koff), &Bls[(nb)+lo0]); glds16(gBl1 + (koff), &Bls[(nb)+lo1]); }
  f32x4 acc[4][4] = {};
  int nt = kld >> 5;
  GSTAGE(0, 0)
  GSTAGE(32, 128*32)
  for (int t = 0; t < nt; ++t){
    if (t + 1 < nt) asm volatile("s_waitcnt vmcnt(8)" ::: "memory");
    else            asm volatile("s_waitcnt vmcnt(0)" ::: "memory");
    __builtin_amdgcn_s_barrier();
    asm volatile("" ::: "memory");
    int cb = (t & 1) * (128*32);
    bf16x8 ah[4], al[4];
    #pragma unroll
    for (int i = 0; i < 4; ++i){
      int Ra = (wr<<6) + (i<<4) + fr;
      int oa = cb + Ra*32 + ((fu ^ ((Ra>>1)&3))<<3);
      ah[i] = *(const bf16x8*)&Ahs[oa];
      al[i] = *(const bf16x8*)&Als[oa];
    }
    #pragma unroll
    for (int j = 0; j < 4; ++j){
      int Rb = (wc<<6) + (j<<4) + fr;
      int ob = cb + Rb*32 + ((fu ^ ((Rb>>1)&3))<<3);
      bf16x8 bh = *(const bf16x8*)&Bhs[ob];
      bf16x8 bl = *(const bf16x8*)&Bls[ob];
      #pragma unroll
      for (int i = 0; i < 4; ++i){
        acc[i][j] = __builtin_amdgcn_mfma_f32_16x16x32_bf16(ah[i], bh, acc[i][j], 0, 0, 0);
        acc[i][j] = __builtin_amdgcn_mfma_f32_16x16x32_bf16(al[i], bh, acc[i][j], 0, 0, 0);
        acc[i][j] = __builtin_amdgcn_mfma_f32_16x16x32_bf16(ah[i], bl, acc[i][j], 0, 0, 0);
      }
    }
    asm volatile("" ::: "memory");
    __builtin_amdgcn_s_barrier();
    if (t + 2 < nt) GSTAGE((t+2) << 5, (t & 1) * (128*32))
  }
  #undef GSTAGE
  int fq = lane >> 4;
  if (Cf){
    #pragma unroll
    for (int j = 0; j < 4; ++j){
      int col = col0 + (wc<<6) + (j<<4) + fr;
      float bv = bias ? bias[col] : 0.f;
      #pragma unroll
      for (int i = 0; i < 4; ++i){
        #pragma unroll
        for (int q = 0; q < 4; ++q){
          int rr = row0 + (wr<<6) + (i<<4) + (fq<<2) + q;
          float v = acc[i][j][q] + bv;
          if (pe) v += pe[(size_t)(rr % TT)*DM + col];
          Cf[(size_t)rr*N + col] = v;
        }
      }
    }
  }
  if (Ch){
    ushort* Lh = smem[0];   // spans smem[0..1]: [128][128] ushorts
    ushort* Ll = smem[2];   // spans smem[2..3]
    __syncthreads();        // all LDS reads from K-loop complete
    #pragma unroll
    for (int j = 0; j < 4; ++j){
      int lcol = (wc<<6) + (j<<4) + fr;
      int col = col0 + lcol;
      float bv = bias ? bias[col] : 0.f;
      #pragma unroll
      for (int i = 0; i < 4; ++i){
        #pragma unroll
        for (int q = 0; q < 4; ++q){
          int lrow = (wr<<6) + (i<<4) + (fq<<2) + q;
          float v = acc[i][j][q] + bv;
          if (pe) v += pe[(size_t)((row0 + lrow) % TT)*DM + col];
          ushort hu, lu; splitbf(v, hu, lu);
          int g = (lrow >> 2) & 7;
          int idx = lrow*128 + ((((lcol>>3) ^ g))<<3) + (lcol & 7);
          Lh[idx] = hu; Ll[idx] = lu;
        }
      }
    }
    __syncthreads();
    #pragma unroll
    for (int pass = 0; pass < 8; ++pass){
      int lrow = pass*16 + (tid >> 4);
      int s = tid & 15;
      int g = (lrow >> 2) & 7;
      int idx = lrow*128 + ((s ^ g)<<3);
      uint4 vh = *(const uint4*)&Lh[idx];
      uint4 vl = *(const uint4*)&Ll[idx];
      size_t off = (size_t)(row0 + lrow)*N + col0 + s*8;
      *(uint4*)&Ch[off] = vh;
      *(uint4*)&Cl[off] = vl;
    }
  }
}

// ---------------- old 64x64 GEMM (kept for the tiny cls matmul, M=32) ----------------
__global__ __launch_bounds__(256)
void gemm_f32(const float* __restrict__ A, const float* __restrict__ Bw,
              float* __restrict__ C, const float* __restrict__ bias,
              float* __restrict__ obf, int M, int N, int K)
{
  __shared__ float As[16][68];
  __shared__ float Bs[16][68];
  int tid = threadIdx.x;
  int row0 = blockIdx.y << 6, col0 = blockIdx.x << 6;
  int ar = tid >> 2, ak = (tid & 3) << 2;
  int bk = tid >> 4, bn = (tid & 15) << 2;
  int n0 = (tid & 15) << 2, m0 = (tid >> 4) << 2;
  float acc[4][4] = {};
  bool arow_ok = (row0 + ar) < M;
  const float* Aldg = A + (size_t)(row0 + ar) * K + ak;
  const float* Bldg = Bw + (size_t)bk * N + col0 + bn;
  for (int k0 = 0; k0 < K; k0 += 16){
    float4 av = make_float4(0.f,0.f,0.f,0.f);
    if (arow_ok) av = *(const float4*)(Aldg + k0);
    float4 bv = *(const float4*)(Bldg + (size_t)k0 * N);
    __syncthreads();
    As[ak+0][ar]=av.x; As[ak+1][ar]=av.y; As[ak+2][ar]=av.z; As[ak+3][ar]=av.w;
    *(float4*)&Bs[bk][bn] = bv;
    __syncthreads();
    #pragma unroll
    for (int kk = 0; kk < 16; ++kk){
      float4 a = *(const float4*)&As[kk][m0];
      float4 b = *(const float4*)&Bs[kk][n0];
      float aa[4] = {a.x,a.y,a.z,a.w};
      float bb[4] = {b.x,b.y,b.z,b.w};
      #pragma unroll
      for (int i = 0; i < 4; ++i)
        #pragma unroll
        for (int j = 0; j < 4; ++j)
          acc[i][j] += aa[i]*bb[j];
    }
  }
  float4 badd = make_float4(0.f,0.f,0.f,0.f);
  if (bias) badd = *(const float4*)(bias + col0 + n0);
  #pragma unroll
  for (int i = 0; i < 4; ++i){
    int gr = row0 + m0 + i;
    if (gr < M){
      float4 r = make_float4(acc[i][0]+badd.x, acc[i][1]+badd.y, acc[i][2]+badd.z, acc[i][3]+badd.w);
      *(float4*)(C + (size_t)gr*N + col0 + n0) = r;
      if (obf) *(float4*)(obf + (size_t)gr*N + col0 + n0) = r;
    }
  }
}

// ---------------- MFMA flash attention (split-bf16, fp32 softmax), XCD-swizzled grid --------
__global__ __launch_bounds__(256)
void fattn_k(const ushort* __restrict__ Xh, const ushort* __restrict__ Xl,
             ushort* __restrict__ oh, ushort* __restrict__ ol)
{
  __shared__ ushort Kh[64][72], Kl[64][72];
  __shared__ ushort Vth[64][72], Vtl[64][72];
  __shared__ ushort Ph[64][72], Pl[64][72];
  int flat = blockIdx.x + (blockIdx.y << 2);
  int wgt = xcd_swz(flat, 4*256);
  int qt = wgt & 3, bh = wgt >> 2;   // same-bh q-tiles colocate on one XCD (K/V L2 reuse)
  int b = bh >> 3, h = bh & 7;
  int tid = threadIdx.x;
  int w = tid >> 6, lane = tid & 63;
  int fr = lane & 15, fu = lane >> 4;
  int qrow_f = qt*64 + w*16 + fr;
  int qtok = b*TT + (qrow_f < TT ? qrow_f : TT-1);
  const ushort* qph = Xh + (size_t)qtok*1536 + h*64 + fu*8;
  const ushort* qpl = Xl + (size_t)qtok*1536 + h*64 + fu*8;
  bf16x8 qh0 = *(const bf16x8*)(qph);
  bf16x8 qh1 = *(const bf16x8*)(qph + 32);
  bf16x8 ql0 = *(const bf16x8*)(qpl);
  bf16x8 ql1 = *(const bf16x8*)(qpl + 32);
  f32x4 o_acc[4] = {};
  float m_i[4], l_i[4];
  #pragma unroll
  for (int q = 0; q < 4; ++q){ m_i[q] = -3e38f; l_i[q] = 0.f; }
  int sr = tid >> 2, sc = (tid & 3) << 4;
  int ktiles = qt + 1;
  for (int kt = 0; kt < ktiles; ++kt){
    __syncthreads();
    {
      int jrow = kt*64 + sr;
      int jtok = b*TT + (jrow < TT ? jrow : TT-1);
      const ushort* kph = Xh + (size_t)jtok*1536 + 512 + h*64 + sc;
      const ushort* kpl = Xl + (size_t)jtok*1536 + 512 + h*64 + sc;
      *(uint4*)&Kh[sr][sc]   = *(const uint4*)kph;
      *(uint4*)&Kh[sr][sc+8] = *(const uint4*)(kph + 8);
      *(uint4*)&Kl[sr][sc]   = *(const uint4*)kpl;
      *(uint4*)&Kl[sr][sc+8] = *(const uint4*)(kpl + 8);
      const ushort* vph = Xh + (size_t)jtok*1536 + 1024 + h*64 + sc;
      const ushort* vpl = Xl + (size_t)jtok*1536 + 1024 + h*64 + sc;
      ushort tv[16];
      *(uint4*)&tv[0] = *(const uint4*)vph;
      *(uint4*)&tv[8] = *(const uint4*)(vph + 8);
      #pragma unroll
      for (int t = 0; t < 16; ++t) Vth[sc + t][sr] = tv[t];
      *(uint4*)&tv[0] = *(const uint4*)vpl;
      *(uint4*)&tv[8] = *(const uint4*)(vpl + 8);
      #pragma unroll
      for (int t = 0; t < 16; ++t) Vtl[sc + t][sr] = tv[t];
    }
    __syncthreads();
    f32x4 sacc[4] = {};
    #pragma unroll
    for (int j = 0; j < 4; ++j){
      bf16x8 kh0 = *(const bf16x8*)&Kh[j*16 + fr][fu*8];
      bf16x8 kh1 = *(const bf16x8*)&Kh[j*16 + fr][32 + fu*8];
      bf16x8 kl0 = *(const bf16x8*)&Kl[j*16 + fr][fu*8];
      bf16x8 kl1 = *(const bf16x8*)&Kl[j*16 + fr][32 + fu*8];
      sacc[j] = __builtin_amdgcn_mfma_f32_16x16x32_bf16(qh0, kh0, sacc[j], 0, 0, 0);
      sacc[j] = __builtin_amdgcn_mfma_f32_16x16x32_bf16(ql0, kh0, sacc[j], 0, 0, 0);
      sacc[j] = __builtin_amdgcn_mfma_f32_16x16x32_bf16(qh0, kl0, sacc[j], 0, 0, 0);
      sacc[j] = __builtin_amdgcn_mfma_f32_16x16x32_bf16(qh1, kh1, sacc[j], 0, 0, 0);
      sacc[j] = __builtin_amdgcn_mfma_f32_16x16x32_bf16(ql1, kh1, sacc[j], 0, 0, 0);
      sacc[j] = __builtin_amdgcn_mfma_f32_16x16x32_bf16(qh1, kl1, sacc[j], 0, 0, 0);
    }
    int rbase = qt*64 + w*16 + (fu<<2);
    int cg = kt*64 + fr;
    float p[4][4];
    #pragma unroll
    for (int q = 0; q < 4; ++q){
      int rg = rbase + q;
      float sv[4];
      #pragma unroll
      for (int j = 0; j < 4; ++j){
        int cj = cg + j*16;
        sv[j] = (cj <= rg && cj < TT) ? sacc[j][q]*0.125f : -3e38f;
      }
      float mx = fmaxf(fmaxf(sv[0],sv[1]), fmaxf(sv[2],sv[3]));
      #pragma unroll
      for (int off = 1; off < 16; off <<= 1) mx = fmaxf(mx, __shfl_xor(mx, off, 64));
      float mnew = fmaxf(m_i[q], mx);
      float al = expf(m_i[q] - mnew);
      l_i[q] *= al;
      o_acc[0][q] *= al; o_acc[1][q] *= al; o_acc[2][q] *= al; o_acc[3][q] *= al;
      float ps = 0.f;
      #pragma unroll
      for (int j = 0; j < 4; ++j){ p[q][j] = expf(sv[j] - mnew); ps += p[q][j]; }
      #pragma unroll
      for (int off = 1; off < 16; off <<= 1) ps += __shfl_xor(ps, off, 64);
      l_i[q] += ps;
      m_i[q] = mnew;
    }
    #pragma unroll
    for (int q = 0; q < 4; ++q){
      int pr = w*16 + (fu<<2) + q;
      #pragma unroll
      for (int j = 0; j < 4; ++j){
        ushort hu, lu; splitbf(p[q][j], hu, lu);
        Ph[pr][j*16 + fr] = hu;
        Pl[pr][j*16 + fr] = lu;
      }
    }
    bf16x8 ph0 = *(const bf16x8*)&Ph[w*16 + fr][fu*8];
    bf16x8 ph1 = *(const bf16x8*)&Ph[w*16 + fr][32 + fu*8];
    bf16x8 pl0 = *(const bf16x8*)&Pl[w*16 + fr][fu*8];
    bf16x8 pl1 = *(const bf16x8*)&Pl[w*16 + fr][32 + fu*8];
    #pragma unroll
    for (int jd = 0; jd < 4; ++jd){
      bf16x8 vh0 = *(const bf16x8*)&Vth[jd*16 + fr][fu*8];
      bf16x8 vh1 = *(const bf16x8*)&Vth[jd*16 + fr][32 + fu*8];
      bf16x8 vl0 = *(const bf16x8*)&Vtl[jd*16 + fr][fu*8];
      bf16x8 vl1 = *(const bf16x8*)&Vtl[jd*16 + fr][32 + fu*8];
      o_acc[jd] = __builtin_amdgcn_mfma_f32_16x16x32_bf16(ph0, vh0, o_acc[jd], 0, 0, 0);
      o_acc[jd] = __builtin_amdgcn_mfma_f32_16x16x32_bf16(pl0, vh0, o_acc[jd], 0, 0, 0);
      o_acc[jd] = __builtin_amdgcn_mfma_f32_16x16x32_bf16(ph0, vl0, o_acc[jd], 0, 0, 0);
      o_acc[jd] = __builtin_amdgcn_mfma_f32_16x16x32_bf16(ph1, vh1, o_acc[jd], 0, 0, 0);
      o_acc[jd] = __builtin_amdgcn_mfma_f32_16x16x32_bf16(pl1, vh1, o_acc[jd], 0, 0, 0);
      o_acc[jd] = __builtin_amdgcn_mfma_f32_16x16x32_bf16(ph1, vl1, o_acc[jd], 0, 0, 0);
    }
  }
  #pragma unroll
  for (int q = 0; q < 4; ++q){
    int rg = qt*64 + w*16 + (fu<<2) + q;
    if (rg < TT){
      float inv = 1.f / l_i[q];
      size_t rowoff = (size_t)(b*TT + rg)*DM + h*64 + fr;
      #pragma unroll
      for (int jd = 0; jd < 4; ++jd){
        float v = o_acc[jd][q] * inv;
        ushort hu, lu; splitbf(v, hu, lu);
        oh[rowoff + jd*16] = hu;
        ol[rowoff + jd*16] = lu;
      }
    }
  }
}

// ---------------- router: reads split-bf16 X pair; LDS-staged transposed weights ----------------
__global__ __launch_bounds__(256)
void router2_k(const ushort* __restrict__ Xh, const ushort* __restrict__ Xl,
               const float* __restrict__ rtW, const float* __restrict__ rtb,
               const float* __restrict__ rnW, const float* __restrict__ rnb, const float* __restrict__ nz,
               int* __restrict__ tok_e, float* __restrict__ tok_g)
{
  __shared__ float Wt[8*513];
  __shared__ float Wn[8*513];
  int tid = threadIdx.x;
  for (int i = tid*4; i < DM*8; i += 1024){
    float4 t = *(const float4*)(rtW + i);
    float4 n = *(const float4*)(rnW + i);
    int d = i >> 3, e = i & 7;
    Wt[(e+0)*513 + d] = t.x; Wt[(e+1)*513 + d] = t.y; Wt[(e+2)*513 + d] = t.z; Wt[(e+3)*513 + d] = t.w;
    Wn[(e+0)*513 + d] = n.x; Wn[(e+1)*513 + d] = n.y; Wn[(e+2)*513 + d] = n.z; Wn[(e+3)*513 + d] = n.w;
  }
  __syncthreads();
  int w = tid >> 6, lane = tid & 63;
  int t = (blockIdx.x << 2) + w;
  const ushort* xh = Xh + (size_t)t * DM;
  const ushort* xl = Xl + (size_t)t * DM;
  float at[8] = {}, an[8] = {};
  #pragma unroll
  for (int u = 0; u < 8; ++u){
    int d = (u<<6) + lane;
    float xv = bf2f(xh[d]) + bf2f(xl[d]);
    #pragma unroll
    for (int e = 0; e < 8; ++e){
      at[e] += xv * Wt[e*513 + d];
      an[e] += xv * Wn[e*513 + d];
    }
  }
  #pragma unroll
  for (int off = 32; off; off >>= 1){
    #pragma unroll
    for (int e = 0; e < 8; ++e){
      at[e] += __shfl_xor(at[e], off, 64);
      an[e] += __shfl_xor(an[e], off, 64);
    }
  }
  if (lane == 0){
    float ns[8];
    #pragma unroll
    for (int e = 0; e < 8; ++e){
      float lt = at[e] + rtb[e];
      float ln_ = an[e] + rnb[e];
      float sp = (ln_ > 0.f) ? (ln_ + log1pf(expf(-ln_))) : log1pf(expf(ln_));
      ns[e] = lt + nz[(size_t)t*8 + e] * sp;
    }
    int i1 = 0; float n1 = ns[0];
    #pragma unroll
    for (int e = 1; e < 8; ++e) if (ns[e] > n1){ n1 = ns[e]; i1 = e; }
    int i2 = -1; float n2 = -3e38f;
    #pragma unroll
    for (int e = 0; e < 8; ++e) if (e != i1 && ns[e] > n2){ n2 = ns[e]; i2 = e; }
    float ex = expf(n2 - n1);
    float inv = 1.f / (1.f + ex);
    tok_e[t*2]   = i1; tok_g[t*2]   = inv;
    tok_e[t*2+1] = i2; tok_g[t*2+1] = ex * inv;
  }
}

// ------- histogram + prefix + slot assignment, wave-ballot aggregated -------
__global__ __launch_bounds__(1024)
void route_assign_k(const int* __restrict__ tok_e, int* __restrict__ offs_g,
                    int* __restrict__ idx_c, int* __restrict__ tok_slot)
{
  __shared__ int hist[NE];
  __shared__ int cur[NE];
  int tid = threadIdx.x;
  int lane = tid & 63;
  if (tid < NE) hist[tid] = 0;
  __syncthreads();
  for (int i = tid; i < BT*2; i += 1024){
    int e = tok_e[i];
    #pragma unroll
    for (int x = 0; x < NE; ++x){
      unsigned long long m = __ballot(e == x);
      if (m && lane == (int)__builtin_ctzll(m)) atomicAdd(&hist[x], __popcll(m));
    }
  }
  __syncthreads();
  if (tid == 0){
    int s = 0;
    for (int e = 0; e < NE; ++e){ offs_g[e] = s; cur[e] = s; s += hist[e]; }
    offs_g[NE] = s;
  }
  __syncthreads();
  for (int i = tid; i < BT*2; i += 1024){
    int e = tok_e[i];
    int p = 0;
    #pragma unroll
    for (int x = 0; x < NE; ++x){
      unsigned long long m = __ballot(e == x);
      if (m){
        int leader = (int)__builtin_ctzll(m);
        int bw = 0;
        if (lane == leader) bw = atomicAdd(&cur[x], __popcll(m));
        bw = __shfl(bw, leader, 64);
        if (e == x) p = bw + __popcll(m & ((lane == 63) ? 0x7fffffffffffffffull : ((1ull << lane) - 1ull)));
      }
    }
    idx_c[p] = i >> 1;
    tok_slot[i] = p;
  }
}

// ---------------- fused expert-weight transpose+convert: eWi and eWo in one launch ----------
__global__ __launch_bounds__(256)
void transconv2_k(const float* __restrict__ eWi, const float* __restrict__ eWo,
                  ushort* __restrict__ WiT, ushort* __restrict__ WoT){
  __shared__ float t[32][33];
  int z = blockIdx.z;
  const float* src; ushort* dst; int R, C, c0, r0;
  if (z < NE){
    src = eWi + (size_t)z*DM*FFD; dst = WiT + (size_t)z*DM*FFD;
    R = DM; C = FFD; c0 = blockIdx.x << 5; r0 = blockIdx.y << 5;
  } else {
    int e = z - NE;
    src = eWo + (size_t)e*FFD*DM; dst = WoT + (size_t)e*FFD*DM;
    R = FFD; C = DM; c0 = blockIdx.y << 5; r0 = blockIdx.x << 5;
  }
  int tx = threadIdx.x & 31, ty = threadIdx.x >> 5;
  #pragma unroll
  for (int i = 0; i < 32; i += 8)
    t[ty+i][tx] = src[(size_t)(r0+ty+i)*C + c0 + tx];
  __syncthreads();
  #pragma unroll
  for (int i = 0; i < 32; i += 8)
    dst[(size_t)(c0+ty+i)*R + r0 + tx] = f2bf(t[tx][ty+i]);
}

// ---------------- MoE expert GEMM, bf16 MFMA, counted-vmcnt 2-deep, XCD swizzle ------------
// MODE 0: A rows gathered via aidx (idx_c) directly from X-hi; bounce-epilogue bf16 out.
// MODE 1: slot-space rows; fp32 out (full-line scalar stores).
template<int MODE>
__global__ __launch_bounds__(256)
void moe_mfma(const ushort* __restrict__ A, const int* __restrict__ aidx,
              const ushort* __restrict__ Bt,
              const float* __restrict__ bias, const int* __restrict__ offs,
              void* __restrict__ Out, int kld, int ldb, int out_ld, int accum)
{
  __shared__ __align__(16) ushort smem[2][2*128*32];
  ushort* As = smem[0];
  ushort* Bs = smem[1];
  int gx = gridDim.x, gy = gridDim.y;
  int nwg = gx * gy * (int)gridDim.z;
  int fblk = blockIdx.x + gx*(blockIdx.y + gy*blockIdx.z);
  int wgt = xcd_swz(fblk, nwg);
  int bx = wgt % gx; wgt /= gx;
  int by = wgt % gy; int bz = wgt / gy;
  int e = bz;
  int base = offs[e], cnt = offs[e+1] - base;
  int row0 = by << 7;
  if (row0 >= cnt) return;
  int col0 = bx << 7;
  int tid = threadIdx.x, lane = tid & 63, w = tid >> 6;
  int wr = w >> 1, wc = w & 1;
  int fr = lane & 15, fu = lane >> 4;
  int srow = 16*w + (lane >> 2);
  int cs = ((lane & 3) ^ ((srow >> 1) & 3)) << 3;
  int s0 = base + row0 + srow;      if (s0 > SLOTS-1) s0 = SLOTS-1;
  int s1 = base + row0 + 64 + srow; if (s1 > SLOTS-1) s1 = SLOTS-1;
  int r0i = (MODE == 0) ? aidx[s0] : s0;
  int r1i = (MODE == 0) ? aidx[s1] : s1;
  const ushort* gA0 = A + (size_t)r0i * kld + cs;
  const ushort* gA1 = A + (size_t)r1i * kld + cs;
  const ushort* Bb = Bt + (size_t)e * ((size_t)FFD*DM);
  const ushort* gB0 = Bb + (size_t)(col0 + srow) * ldb + cs;
  const ushort* gB1 = Bb + (size_t)(col0 + 64 + srow) * ldb + cs;
  int lo0 = (16*w)*32, lo1 = (64+16*w)*32;
  #define MSTAGE(koff, nb) { \
    glds16(gA0 + (koff), &As[(nb)+lo0]); glds16(gA1 + (koff), &As[(nb)+lo1]); \
    glds16(gB0 + (koff), &Bs[(nb)+lo0]); glds16(gB1 + (koff), &Bs[(nb)+lo1]); }
  f32x4 acc[4][4] = {};
  int nt = kld >> 5;
  MSTAGE(0, 0)
  MSTAGE(32, 128*32)
  for (int t = 0; t < nt; ++t){
    if (t + 1 < nt) asm volatile("s_waitcnt vmcnt(4)" ::: "memory");
    else            asm volatile("s_waitcnt vmcnt(0)" ::: "memory");
    __builtin_amdgcn_s_barrier();
    asm volatile("" ::: "memory");
    int cb = (t & 1) * (128*32);
    bf16x8 af[4], bf[4];
    #pragma unroll
    for (int i = 0; i < 4; ++i){
      int Ra = (wr<<6) + (i<<4) + fr;
      af[i] = *(const bf16x8*)&As[cb + Ra*32 + ((fu ^ ((Ra>>1)&3))<<3)];
      int Rb = (wc<<6) + (i<<4) + fr;
      bf[i] = *(const bf16x8*)&Bs[cb + Rb*32 + ((fu ^ ((Rb>>1)&3))<<3)];
    }
    #pragma unroll
    for (int i = 0; i < 4; ++i)
      #pragma unroll
      for (int j = 0; j < 4; ++j)
        acc[i][j] = __builtin_amdgcn_mfma_f32_16x16x32_bf16(af[i], bf[j], acc[i][j], 0, 0, 0);
    asm volatile("" ::: "memory");
    __builtin_amdgcn_s_barrier();
    if (t + 2 < nt) MSTAGE((t+2) << 5, (t & 1) * (128*32))
  }
  #undef MSTAGE
  int fq = lane >> 4;
  if (MODE == 0){
    // LDS-bounce epilogue: relu+bias -> bf16 tile in LDS (swizzled), flush full lines
    ushort* Ls = smem[0];   // 16384 ushorts = [128][128]
    __syncthreads();
    #pragma unroll
    for (int j = 0; j < 4; ++j){
      int lcol = (wc<<6) + (j<<4) + fr;
      float bv = bias[(size_t)e*FFD + col0 + lcol];
      #pragma unroll
      for (int i = 0; i < 4; ++i){
        #pragma unroll
        for (int q = 0; q < 4; ++q){
          int lrow = (wr<<6) + (i<<4) + (fq<<2) + q;
          float vv = acc[i][j][q] + bv;
          int g = (lrow >> 2) & 7;
          Ls[lrow*128 + ((((lcol>>3) ^ g))<<3) + (lcol & 7)] = f2bf(fmaxf(vv, 0.f));
        }
      }
    }
    __syncthreads();
    #pragma unroll
    for (int pass = 0; pass < 8; ++pass){
      int lrow = pass*16 + (tid >> 4);
      int s = tid & 15;
      int g = (lrow >> 2) & 7;
      uint4 v = *(const uint4*)&Ls[lrow*128 + ((s ^ g)<<3)];
      int gr = row0 + lrow;
      if (gr < cnt)
        *(uint4*)&((ushort*)Out)[(size_t)(base+gr)*out_ld + col0 + s*8] = v;
    }
  } else {
    #pragma unroll
    for (int j = 0; j < 4; ++j){
      int col = col0 + (wc<<6) + (j<<4) + fr;
      float bv = bias[(size_t)e*DM + col];
      #pragma unroll
      for (int i = 0; i < 4; ++i){
        #pragma unroll
        for (int q = 0; q < 4; ++q){
          int rr = row0 + (wr<<6) + (i<<4) + (fq<<2) + q;
          if (rr < cnt){
            float* yp = (float*)Out + (size_t)(base+rr)*out_ld + col;
            *yp = acc[i][j][q] + (accum ? *yp : bv);
          }
        }
      }
    }
  }
}

// ---------------- gated combine + layernorm; output as split-bf16 ----------------
__global__ __launch_bounds__(256)
void combine_ln_k(const float* __restrict__ Ye, const int* __restrict__ tok_slot,
                  const float* __restrict__ tok_g, const float* __restrict__ g,
                  const float* __restrict__ bb, ushort* __restrict__ oh, ushort* __restrict__ ol)
{
  int t = blockIdx.x, tid = threadIdx.x;
  int s1 = tok_slot[t*2], s2 = tok_slot[t*2+1];
  float g1 = tok_g[t*2], g2 = tok_g[t*2+1];
  const float* y1 = Ye + (size_t)s1*DM;
  const float* y2 = Ye + (size_t)s2*DM;
  float v0 = g1*y1[tid]     + g2*y2[tid];
  float v1 = g1*y1[tid+256] + g2*y2[tid+256];
  __shared__ float red[8];
  int w = tid >> 6, lane = tid & 63;
  float s = v0 + v1;
  #pragma unroll
  for (int off = 32; off; off >>= 1) s += __shfl_xor(s, off, 64);
  if (lane == 0) red[w] = s;
  __syncthreads();
  float mu = (red[0]+red[1]+red[2]+red[3]) * (1.f/512.f);
  float d0 = v0 - mu, d1 = v1 - mu;
  float q2 = d0*d0 + d1*d1;
  #pragma unroll
  for (int off = 32; off; off >>= 1) q2 += __shfl_xor(q2, off, 64);
  if (lane == 0) red[4+w] = q2;
  __syncthreads();
  float var = (red[4]+red[5]+red[6]+red[7]) * (1.f/512.f);
  float r = 1.f / sqrtf(var + 1e-5f);
  float r0v = d0*r*g[tid]     + bb[tid];
  float r1v = d1*r*g[tid+256] + bb[tid+256];
  ushort hu, lu;
  splitbf(r0v, hu, lu);
  oh[(size_t)t*DM + tid] = hu; ol[(size_t)t*DM + tid] = lu;
  splitbf(r1v, hu, lu);
  oh[(size_t)t*DM + tid + 256] = hu; ol[(size_t)t*DM + tid + 256] = lu;
}

// ---------------- global = sum over T of second_vector ----------------
__global__ void gsum_k(const float* __restrict__ sv, float* __restrict__ gb, float* __restrict__ gout){
  int i = blockIdx.x*256 + threadIdx.x;
  int b = i >> 9, d = i & 511;
  const float* p = sv + (size_t)b*TT*DM + d;
  float s = 0.f;
  for (int t = 0; t < TT; ++t) s += p[(size_t)t*DM];
  gb[i] = s; gout[i] = s;
}

extern "C" void kernel_launch(void* const* d_in, const int* in_sizes, int n_in,
                              void* d_out, int out_size, void* d_ws, size_t ws_size,
                              hipStream_t stream)
{
  (void)in_sizes; (void)n_in; (void)out_size;
  const float* xin   = (const float*)d_in[0];
  const float* pembW = (const float*)d_in[1];
  const float* pembB = (const float*)d_in[2];
  const float* vecW  = (const float*)d_in[3];
  const float* vecB  = (const float*)d_in[4];
  const float* clsW  = (const float*)d_in[5];
  const float* clsB  = (const float*)d_in[6];
  float* out = (float*)d_out;

  // ---- workspace budget (floats). FoldW/PW live inside the QKV/H1 region. ----
  const size_t QKV_SH  = (size_t)2*BT*1536;
  const size_t RMIN_SH = QKV_SH + (size_t)2*1536*DM + (size_t)2*DM*DM;   // + FoldW pair + PW pair
  const size_t FIXF =
      (size_t)SLOTS*DM                         // Yexp fp32
    + (size_t)2*ABUF                           // S0/S1 split pairs (4*ABUF shorts)
    + (size_t)NE*FFD*DM                        // WiT+WoT shorts
    + (size_t)256*DM                           // Pemb pair shorts->floats
    + (size_t)DM*DM                            // Vec pair
    + (size_t)3*DM*DM                          // QkvW pair
    + (size_t)DM*DM                            // WoS pair
    + (size_t)TT*DM + 2048                     // posenc + bfold
    + 16384*2 + SLOTS + SLOTS*3 + 256;
  int fcw = 256;
  for (int cand = 2048; cand >= 256; cand >>= 1){
    size_t reg_sh = (size_t)SLOTS*cand > RMIN_SH ? (size_t)SLOTS*cand : RMIN_SH;
    size_t need = (FIXF + reg_sh/2) * sizeof(float);
    if (need <= ws_size){ fcw = cand; break; }
  }
  size_t region_sh = (size_t)SLOTS*fcw > RMIN_SH ? (size_t)SLOTS*fcw : RMIN_SH;

  float* ws = (float*)d_ws;
  float* Yexp = ws;
  ushort* S0h = (ushort*)(Yexp + (size_t)SLOTS*DM);
  ushort* S0l = S0h + ABUF;
  ushort* S1h = S0l + ABUF;
  ushort* S1l = S1h + ABUF;
  ushort* region = S1l + ABUF;
  ushort* WiT  = region + region_sh;
  ushort* WoT  = WiT + (size_t)NE*FFD*DM;
  ushort* PembH = WoT + (size_t)NE*FFD*DM;
  ushort* PembL = PembH + 256*DM;
  ushort* VecH = PembL + 256*DM;
  ushort* VecL = VecH + DM*DM;
  ushort* QkvWH = VecL + DM*DM;
  ushort* QkvWL = QkvWH + 3*DM*DM;
  ushort* WoSH = QkvWL + 3*DM*DM;
  ushort* WoSL = WoSH + DM*DM;
  float* pe    = (float*)(WoSL + DM*DM);
  float* bfold = pe + TT*DM;
  float* gbv   = bfold + 2048;
  float* clsbuf= gbv + 16384;
  float* tok_g = clsbuf + 16384;
  int* tok_e   = (int*)(tok_g + SLOTS);
  int* tok_slot= tok_e + SLOTS;
  int* idx_c   = tok_slot + SLOTS;
  int* offs    = idx_c + SLOTS;      // 9 ints
  // region internals (time-multiplexed)
  ushort* QKVh = region;
  ushort* QKVl = region + (size_t)BT*1536;
  ushort* FoldWH = region + QKV_SH;
  ushort* FoldWL = FoldWH + (size_t)1536*DM;
  ushort* PWh  = FoldWL + (size_t)1536*DM;
  ushort* PWl  = PWh + (size_t)DM*DM;
  ushort* H1b  = region;
  ushort* PATh = region;
  ushort* PATl = region + (size_t)BT*256;

  patchify_k<<<dim3(BT), dim3(256), 0, stream>>>(xin, PATh, PATl);
  posenc_k<<<dim3(TT), dim3(512), 0, stream>>>(pe);
  wsplit_k<<<dim3(16, 8), dim3(256), 0, stream>>>(pembW, PembH, PembL, 256, DM);
  wsplit_k<<<dim3(16, 16), dim3(256), 0, stream>>>(vecW, VecH, VecL, DM, DM);
  // h = patches @ pembW + b + posenc -> split S0
  gemm_s<<<dim3(4,49), dim3(256), 0, stream>>>(PATh, PATl, PembH, PembL, pembB, pe,
                                               nullptr, S0h, S0l, DM, 256);

  ushort *INh = S0h, *INl = S0l, *TPh = S1h, *TPl = S1l;
  for (int l = 0; l < 2; ++l){
    int base = 7 + 18*l;
    const float* pW  = (const float*)d_in[base+0];
    const float* pb  = (const float*)d_in[base+1];
    const float* Wq  = (const float*)d_in[base+2];
    const float* Wk  = (const float*)d_in[base+3];
    const float* Wv  = (const float*)d_in[base+4];
    const float* Wo  = (const float*)d_in[base+5];
    const float* bo  = (const float*)d_in[base+6];
    const float* rtW = (const float*)d_in[base+7];
    const float* rtb = (const float*)d_in[base+8];
    const float* rnW = (const float*)d_in[base+9];
    const float* rnb = (const float*)d_in[base+10];
    const float* eWi = (const float*)d_in[base+11];
    const float* ebi = (const float*)d_in[base+12];
    const float* eWo = (const float*)d_in[base+13];
    const float* ebo = (const float*)d_in[base+14];
    const float* lng = (const float*)d_in[base+15];
    const float* lnb = (const float*)d_in[base+16];
    const float* nz  = (const float*)d_in[base+17];

    // dense attn weights (Qkv^T, Wo^T) + pW elementwise split, one launch
    wsplit5e_k<<<dim3(16,16,5), dim3(256), 0, stream>>>(Wq, Wk, Wv, Wo, pW,
                                                        QkvWH, QkvWL, WoSH, WoSL, PWh, PWl);
    // fold in-projection into QKV: FoldW[m][i] = sum_d Wqkv^T[m][d] * pW[i][d]
    gemm_s<<<dim3(4,12), dim3(256), 0, stream>>>(QkvWH, QkvWL, PWh, PWl, nullptr, nullptr,
                                                 nullptr, FoldWH, FoldWL, DM, DM);
    bfold_k<<<dim3(384), dim3(256), 0, stream>>>(pb, Wq, Wk, Wv, bfold);
    // QKV = IN @ FoldW^T + bfold  (split pair [BT][1536])
    gemm_s<<<dim3(12,49), dim3(256), 0, stream>>>(INh, INl, FoldWH, FoldWL, bfold, nullptr,
                                                 nullptr, QKVh, QKVl, 1536, DM);
    // attention: QKV -> IN (split)
    fattn_k<<<dim3(4,256), dim3(256), 0, stream>>>(QKVh, QKVl, INh, INl);
    // output projection: IN -> TP (router + MoE input)
    gemm_s<<<dim3(4,49), dim3(256), 0, stream>>>(INh, INl, WoSH, WoSL, bo, nullptr,
                                                 nullptr, TPh, TPl, DM, DM);
    // expert weights -> bf16 transposed (single fused launch)
    transconv2_k<<<dim3(64, 16, 2*NE), dim3(256), 0, stream>>>(eWi, eWo, WiT, WoT);
    // routing
    router2_k<<<dim3(BT/4), dim3(256), 0, stream>>>(TPh, TPl, rtW, rtb, rnW, rnb, nz, tok_e, tok_g);
    route_assign_k<<<dim3(1), dim3(1024), 0, stream>>>(tok_e, offs, idx_c, tok_slot);
    // experts (QKV/FoldW region dead now; H1b aliases it); A gathered directly via idx_c
    for (int c0 = 0; c0 < FFD; c0 += fcw){
      moe_mfma<0><<<dim3(fcw/128, 49, NE), dim3(256), 0, stream>>>(
          TPh, idx_c, WiT + (size_t)c0*DM, ebi + c0, offs, (void*)H1b, DM, DM, fcw, 0);
      moe_mfma<1><<<dim3(DM/128, 49, NE), dim3(256), 0, stream>>>(
          H1b, nullptr, WoT + c0, ebo, offs, (void*)Yexp, fcw, FFD, DM, c0);
    }
    // combine + LN -> IN (split)
    combine_ln_k<<<dim3(BT), dim3(256), 0, stream>>>(Yexp, tok_slot, tok_g, lng, lnb, INh, INl);
    // vector projection: IN -> out mirror (fp32) + TP (next layer input, split)
    gemm_s<<<dim3(4,49), dim3(256), 0, stream>>>(INh, INl, VecH, VecL, vecB, nullptr,
                                                 out + (size_t)l*ABUF, TPh, TPl, DM, DM);
    ushort* th = INh; INh = TPh; TPh = th;
    ushort* tl = INl; INl = TPl; TPl = tl;
  }

  gsum_k<<<dim3(64), dim3(256), 0, stream>>>(out + ABUF, gbv, out + 2*ABUF);
  gemm_f32<<<dim3(8,1), dim3(256), 0, stream>>>(gbv, clsW, clsbuf, clsB, out + 2*ABUF + 16384, 32, DM, DM);
}